// Round 1
// baseline (2755.067 us; speedup 1.0000x reference)
//
#include <hip/hip_runtime.h>
#include <hip/hip_bf16.h>

#define BDIM 256
#define NPTS (8 * 2048)           // B*N
#define CC 128
#define DD 32
#define FF 512
#define NN 2048
#define SCALE 0.08838834764831845f   // 1/sqrt(128)

// ---------------- kernel 1: q/k/v projections ----------------
// grid: NPTS/16 blocks, 256 thr. Each block: 16 points.
__global__ void k_proj(const float* __restrict__ x, const float* __restrict__ Wq,
                       const float* __restrict__ Wk, const float* __restrict__ Wv,
                       const float* __restrict__ bv,
                       float* __restrict__ q, float* __restrict__ k, float* __restrict__ v) {
    __shared__ float xs[16][CC];
    long base = (long)blockIdx.x * 16;
    const float4* xg = (const float4*)(x + base * CC);
    float4* xs4 = (float4*)&xs[0][0];
    for (int i = threadIdx.x; i < 16 * (CC / 4); i += BDIM) xs4[i] = xg[i];
    __syncthreads();
    // 16 points * 192 out-ch = 3072 outputs -> 12 per thread
    for (int rep = 0; rep < 12; ++rep) {
        int id = rep * BDIM + threadIdx.x;
        int p = id / 192, oc = id % 192;
        const float* wrow;
        float bias = 0.f;
        float* outp;
        if (oc < 32) {
            wrow = Wq + oc * CC;            outp = q + (base + p) * DD + oc;
        } else if (oc < 64) {
            wrow = Wk + (oc - 32) * CC;     outp = k + (base + p) * DD + (oc - 32);
        } else {
            wrow = Wv + (oc - 64) * CC;  bias = bv[oc - 64];
            outp = v + (base + p) * CC + (oc - 64);
        }
        const float4* w4 = (const float4*)wrow;
        const float4* x4 = (const float4*)&xs[p][0];
        float s = bias;
        #pragma unroll
        for (int j = 0; j < CC / 4; ++j) {
            float4 a = x4[j], w = w4[j];
            s += a.x * w.x + a.y * w.y + a.z * w.z + a.w * w.w;
        }
        *outp = s;
    }
}

// ---------------- kernel 2: per-row softmax stats ----------------
// grid: B * N/32 = 512 blocks. Block handles 32 rows (n), loops m in tiles of 64.
__global__ void k_rowstats(const float* __restrict__ q, const float* __restrict__ k,
                           float* __restrict__ rowmax, float* __restrict__ rowinv) {
    __shared__ float qs[32][33];
    __shared__ float ks[64][33];
    int b = blockIdx.x >> 6;            // /64
    int n0 = (blockIdx.x & 63) * 32;
    const float* qb = q + ((long)b * NN + n0) * DD;
    for (int i = threadIdx.x; i < 32 * DD; i += BDIM) qs[i >> 5][i & 31] = qb[i];
    int r = threadIdx.x >> 3;           // 0..31 row within tile
    int c8 = threadIdx.x & 7;           // 8 threads share a row
    float mx = -1e30f, sm = 0.f;
    for (int mt = 0; mt < NN; mt += 64) {
        __syncthreads();
        const float* kb = k + ((long)b * NN + mt) * DD;
        for (int i = threadIdx.x; i < 64 * DD; i += BDIM) ks[i >> 5][i & 31] = kb[i];
        __syncthreads();
        #pragma unroll
        for (int i = 0; i < 8; ++i) {
            int m = c8 * 8 + i;
            float e = 0.f;
            #pragma unroll
            for (int d = 0; d < DD; ++d) e += qs[r][d] * ks[m][d];
            e *= SCALE;
            float nm = fmaxf(mx, e);
            sm = sm * __expf(mx - nm) + __expf(e - nm);
            mx = nm;
        }
    }
    // combine across the 8 threads of a row (consecutive lanes within a wave)
    for (int off = 4; off; off >>= 1) {
        float omx = __shfl_xor(mx, off, 8);
        float osm = __shfl_xor(sm, off, 8);
        float nm = fmaxf(mx, omx);
        sm = sm * __expf(mx - nm) + osm * __expf(omx - nm);
        mx = nm;
    }
    if (c8 == 0) {
        rowmax[(long)b * NN + n0 + r] = mx;
        rowinv[(long)b * NN + n0 + r] = 1.f / sm;
    }
}

// ---------------- kernel 3: x_r = sum_n A[n,m] * v[n,c] ----------------
// grid: B * N/64 = 256 blocks. Block: m-tile of 64, all c. Loops n in tiles of 32.
// Thread register tile: 4 m x 8 c.
__global__ void k_pv(const float* __restrict__ q, const float* __restrict__ k,
                     const float* __restrict__ v, const float* __restrict__ rowmax,
                     const float* __restrict__ rowinv, float* __restrict__ xr) {
    __shared__ float ks[64][33];
    __shared__ float qs[32][33];
    __shared__ float vs[32][CC];
    __shared__ float as[32][64];
    __shared__ float rmx[32], rin[32];
    int b = blockIdx.x >> 5;            // N/64 = 32 m-tiles per b
    int m0 = (blockIdx.x & 31) * 64;
    const float* kb = k + ((long)b * NN + m0) * DD;
    for (int i = threadIdx.x; i < 64 * DD; i += BDIM) ks[i >> 5][i & 31] = kb[i];
    int mg = threadIdx.x & 15;          // m sub-group (4 m's)
    int cg = threadIdx.x >> 4;          // c sub-group (8 c's)
    float acc[4][8];
    #pragma unroll
    for (int i = 0; i < 4; ++i)
        #pragma unroll
        for (int j = 0; j < 8; ++j) acc[i][j] = 0.f;
    for (int nt = 0; nt < NN; nt += 32) {
        __syncthreads();
        const float* qb = q + ((long)b * NN + nt) * DD;
        for (int i = threadIdx.x; i < 32 * DD; i += BDIM) qs[i >> 5][i & 31] = qb[i];
        const float* vb = v + ((long)b * NN + nt) * CC;
        for (int i = threadIdx.x; i < 32 * CC; i += BDIM) ((float*)vs)[i] = vb[i];
        if (threadIdx.x < 32) {
            rmx[threadIdx.x] = rowmax[(long)b * NN + nt + threadIdx.x];
            rin[threadIdx.x] = rowinv[(long)b * NN + nt + threadIdx.x];
        }
        __syncthreads();
        // A tile: 32n x 64m -> 8 per thread (wave: same n, 64 distinct m)
        #pragma unroll
        for (int i2 = 0; i2 < 8; ++i2) {
            int id = i2 * BDIM + threadIdx.x;
            int n = id >> 6, m = id & 63;
            float e = 0.f;
            #pragma unroll
            for (int d = 0; d < DD; ++d) e += qs[n][d] * ks[m][d];
            as[n][m] = __expf(e * SCALE - rmx[n]) * rin[n];
        }
        __syncthreads();
        #pragma unroll 4
        for (int n = 0; n < 32; ++n) {
            float4 a4 = *(const float4*)&as[n][mg * 4];
            float4 v0 = *(const float4*)&vs[n][cg * 8];
            float4 v1 = *(const float4*)&vs[n][cg * 8 + 4];
            const float* ap = (const float*)&a4;
            #pragma unroll
            for (int mi = 0; mi < 4; ++mi) {
                float a = ap[mi];
                acc[mi][0] += a * v0.x; acc[mi][1] += a * v0.y;
                acc[mi][2] += a * v0.z; acc[mi][3] += a * v0.w;
                acc[mi][4] += a * v1.x; acc[mi][5] += a * v1.y;
                acc[mi][6] += a * v1.z; acc[mi][7] += a * v1.w;
            }
        }
    }
    #pragma unroll
    for (int mi = 0; mi < 4; ++mi) {
        int m = m0 + mg * 4 + mi;
        float* o = xr + ((long)b * NN + m) * CC + cg * 8;
        float4 o0 = make_float4(acc[mi][0], acc[mi][1], acc[mi][2], acc[mi][3]);
        float4 o1 = make_float4(acc[mi][4], acc[mi][5], acc[mi][6], acc[mi][7]);
        *(float4*)o = o0;
        *(float4*)(o + 4) = o1;
    }
}

// ---------------- kernel 4: h = x + relu(BN1(Wt (x - xr) + bt)) ----------------
__global__ void k_tproj(const float* __restrict__ x, const float* __restrict__ xr,
                        const float* __restrict__ Wt, const float* __restrict__ bt,
                        const float* __restrict__ g1, const float* __restrict__ b1,
                        const float* __restrict__ m1, const float* __restrict__ v1,
                        float* __restrict__ h) {
    __shared__ float ds[16][CC];
    long base = (long)blockIdx.x * 16;
    const float4* xg = (const float4*)(x + base * CC);
    const float4* rg = (const float4*)(xr + base * CC);
    float4* ds4 = (float4*)&ds[0][0];
    for (int i = threadIdx.x; i < 16 * (CC / 4); i += BDIM) {
        float4 a = xg[i], r = rg[i];
        ds4[i] = make_float4(a.x - r.x, a.y - r.y, a.z - r.z, a.w - r.w);
    }
    __syncthreads();
    for (int rep = 0; rep < 8; ++rep) {
        int id = rep * BDIM + threadIdx.x;
        int p = id >> 7, o = id & 127;
        const float4* w4 = (const float4*)(Wt + o * CC);
        const float4* d4 = (const float4*)&ds[p][0];
        float s = bt[o];
        #pragma unroll
        for (int j = 0; j < CC / 4; ++j) {
            float4 a = d4[j], w = w4[j];
            s += a.x * w.x + a.y * w.y + a.z * w.z + a.w * w.w;
        }
        float sc = g1[o] * rsqrtf(v1[o] + 1e-5f);
        float t = (s - m1[o]) * sc + b1[o];
        t = fmaxf(t, 0.f);
        h[(base + p) * CC + o] = x[(base + p) * CC + o] + t;
    }
}

// ---------------- kernel 5: out = BN2(h + W2 relu(W1 h + bf1) + bf2) ----------------
// 16 points per block; f kept in LDS (no global f buffer).
__global__ void k_ff(const float* __restrict__ h, const float* __restrict__ W1,
                     const float* __restrict__ bf1, const float* __restrict__ W2,
                     const float* __restrict__ bf2,
                     const float* __restrict__ g2, const float* __restrict__ b2,
                     const float* __restrict__ m2, const float* __restrict__ v2,
                     float* __restrict__ out) {
    __shared__ float hs[16][CC];
    __shared__ float fs[16][FF];
    long base = (long)blockIdx.x * 16;
    const float4* hg = (const float4*)(h + base * CC);
    float4* hs4 = (float4*)&hs[0][0];
    for (int i = threadIdx.x; i < 16 * (CC / 4); i += BDIM) hs4[i] = hg[i];
    __syncthreads();
    // phase 1: 16*512 outputs -> 32 per thread
    for (int rep = 0; rep < 32; ++rep) {
        int id = rep * BDIM + threadIdx.x;
        int p = id >> 9, f = id & 511;
        const float4* w4 = (const float4*)(W1 + f * CC);
        const float4* h4 = (const float4*)&hs[p][0];
        float s = bf1[f];
        #pragma unroll
        for (int j = 0; j < CC / 4; ++j) {
            float4 a = h4[j], w = w4[j];
            s += a.x * w.x + a.y * w.y + a.z * w.z + a.w * w.w;
        }
        fs[p][f] = fmaxf(s, 0.f);
    }
    __syncthreads();
    // phase 2: 16*128 outputs -> 8 per thread
    for (int rep = 0; rep < 8; ++rep) {
        int id = rep * BDIM + threadIdx.x;
        int p = id >> 7, o = id & 127;
        const float4* w4 = (const float4*)(W2 + o * FF);
        const float4* f4 = (const float4*)&fs[p][0];
        float s = bf2[o];
        #pragma unroll
        for (int j = 0; j < FF / 4; ++j) {
            float4 a = f4[j], w = w4[j];
            s += a.x * w.x + a.y * w.y + a.z * w.z + a.w * w.w;
        }
        float r = hs[p][o] + s;
        float sc = g2[o] * rsqrtf(v2[o] + 1e-5f);
        out[(base + p) * CC + o] = (r - m2[o]) * sc + b2[o];
    }
}

extern "C" void kernel_launch(void* const* d_in, const int* in_sizes, int n_in,
                              void* d_out, int out_size, void* d_ws, size_t ws_size,
                              hipStream_t stream) {
    const float* x   = (const float*)d_in[0];
    const float* Wq  = (const float*)d_in[1];
    const float* Wk  = (const float*)d_in[2];
    const float* Wv  = (const float*)d_in[3];
    const float* bv  = (const float*)d_in[4];
    const float* Wt  = (const float*)d_in[5];
    const float* bt  = (const float*)d_in[6];
    const float* g1  = (const float*)d_in[7];
    const float* b1  = (const float*)d_in[8];
    const float* m1  = (const float*)d_in[9];
    const float* v1  = (const float*)d_in[10];
    const float* W1  = (const float*)d_in[11];
    const float* bf1 = (const float*)d_in[12];
    const float* W2  = (const float*)d_in[13];
    const float* bf2 = (const float*)d_in[14];
    const float* g2  = (const float*)d_in[15];
    const float* b2  = (const float*)d_in[16];
    const float* m2  = (const float*)d_in[17];
    const float* v2  = (const float*)d_in[18];
    float* out = (float*)d_out;

    float* ws  = (float*)d_ws;
    float* q   = ws;                       // NPTS*32
    float* k   = q + (long)NPTS * DD;      // NPTS*32
    float* v   = k + (long)NPTS * DD;      // NPTS*128
    float* xr  = v + (long)NPTS * CC;      // NPTS*128
    float* h   = xr + (long)NPTS * CC;     // NPTS*128
    float* rmx = h + (long)NPTS * CC;      // NPTS
    float* rin = rmx + NPTS;               // NPTS

    k_proj<<<NPTS / 16, BDIM, 0, stream>>>(x, Wq, Wk, Wv, bv, q, k, v);
    k_rowstats<<<8 * (NN / 32), BDIM, 0, stream>>>(q, k, rmx, rin);
    k_pv<<<8 * (NN / 64), BDIM, 0, stream>>>(q, k, v, rmx, rin, xr);
    k_tproj<<<NPTS / 16, BDIM, 0, stream>>>(x, xr, Wt, bt, g1, b1, m1, v1, h);
    k_ff<<<NPTS / 16, BDIM, 0, stream>>>(h, W1, bf1, W2, bf2, g2, b2, m2, v2, out);
}

// Round 2
// 1036.888 us; speedup vs baseline: 2.6571x; 2.6571x over previous
//
#include <hip/hip_runtime.h>
#include <hip/hip_bf16.h>

#define BDIM 256
#define NPTS (8 * 2048)           // B*N
#define CC 128
#define DD 32
#define FF 512
#define NN 2048
#define SCALE 0.08838834764831845f   // 1/sqrt(128)

typedef float f32x4 __attribute__((ext_vector_type(4)));
typedef short s16x8 __attribute__((ext_vector_type(8)));
typedef unsigned short ushort_t;

__device__ __forceinline__ ushort_t bf16r(float x) {
    __hip_bfloat16 h = __float2bfloat16(x);
    return *reinterpret_cast<ushort_t*>(&h);
}
__device__ __forceinline__ float bf16tof(ushort_t u) {
    unsigned v = ((unsigned)u) << 16;
    return *reinterpret_cast<float*>(&v);
}

// ---------------- kernel 0: f32 -> bf16 weight conversion ----------------
__global__ void k_cvt(const float* __restrict__ a, ushort_t* __restrict__ o, int n4) {
    int i = blockIdx.x * BDIM + threadIdx.x;
    if (i < n4) {
        float4 v = ((const float4*)a)[i];
        ushort_t r0 = bf16r(v.x), r1 = bf16r(v.y), r2 = bf16r(v.z), r3 = bf16r(v.w);
        o[i*4+0] = r0; o[i*4+1] = r1; o[i*4+2] = r2; o[i*4+3] = r3;
    }
}

// ---------------- kernel 1: q/k/v projections ----------------
__global__ void k_proj(const float* __restrict__ x, const float* __restrict__ Wq,
                       const float* __restrict__ Wk, const float* __restrict__ Wv,
                       const float* __restrict__ bv,
                       float* __restrict__ q, float* __restrict__ k, float* __restrict__ v) {
    __shared__ float xs[16][CC];
    long base = (long)blockIdx.x * 16;
    const float4* xg = (const float4*)(x + base * CC);
    float4* xs4 = (float4*)&xs[0][0];
    for (int i = threadIdx.x; i < 16 * (CC / 4); i += BDIM) xs4[i] = xg[i];
    __syncthreads();
    for (int rep = 0; rep < 12; ++rep) {
        int id = rep * BDIM + threadIdx.x;
        int p = id / 192, oc = id % 192;
        const float* wrow;
        float bias = 0.f;
        float* outp;
        if (oc < 32) {
            wrow = Wq + oc * CC;            outp = q + (base + p) * DD + oc;
        } else if (oc < 64) {
            wrow = Wk + (oc - 32) * CC;     outp = k + (base + p) * DD + (oc - 32);
        } else {
            wrow = Wv + (oc - 64) * CC;  bias = bv[oc - 64];
            outp = v + (base + p) * CC + (oc - 64);
        }
        const float4* w4 = (const float4*)wrow;
        const float4* x4 = (const float4*)&xs[p][0];
        float s = bias;
        #pragma unroll
        for (int j = 0; j < CC / 4; ++j) {
            float4 a = x4[j], w = w4[j];
            s += a.x * w.x + a.y * w.y + a.z * w.z + a.w * w.w;
        }
        *outp = s;
    }
}

// ---------------- kernel 2: per-row softmax stats ----------------
__global__ void k_rowstats(const float* __restrict__ q, const float* __restrict__ k,
                           float* __restrict__ rowmax, float* __restrict__ rowinv) {
    __shared__ float qs[32][33];
    __shared__ float ks[64][33];
    int b = blockIdx.x >> 6;
    int n0 = (blockIdx.x & 63) * 32;
    const float* qb = q + ((long)b * NN + n0) * DD;
    for (int i = threadIdx.x; i < 32 * DD; i += BDIM) qs[i >> 5][i & 31] = qb[i];
    int r = threadIdx.x >> 3;
    int c8 = threadIdx.x & 7;
    float mx = -1e30f, sm = 0.f;
    for (int mt = 0; mt < NN; mt += 64) {
        __syncthreads();
        const float* kb = k + ((long)b * NN + mt) * DD;
        for (int i = threadIdx.x; i < 64 * DD; i += BDIM) ks[i >> 5][i & 31] = kb[i];
        __syncthreads();
        #pragma unroll
        for (int i = 0; i < 8; ++i) {
            int m = c8 * 8 + i;
            float e = 0.f;
            #pragma unroll
            for (int d = 0; d < DD; ++d) e += qs[r][d] * ks[m][d];
            e *= SCALE;
            float nm = fmaxf(mx, e);
            sm = sm * __expf(mx - nm) + __expf(e - nm);
            mx = nm;
        }
    }
    for (int off = 4; off; off >>= 1) {
        float omx = __shfl_xor(mx, off, 8);
        float osm = __shfl_xor(sm, off, 8);
        float nm = fmaxf(mx, omx);
        sm = sm * __expf(mx - nm) + osm * __expf(omx - nm);
        mx = nm;
    }
    if (c8 == 0) {
        rowmax[(long)b * NN + n0 + r] = mx;
        rowinv[(long)b * NN + n0 + r] = 1.f / sm;
    }
}

// ---------------- kernel 3: x_r[m,c] = sum_n A[n,m] * v[n,c] ----------------
// grid: B * N/32 = 512 blocks; m-tile 32, n-tile 64. Thread tile 4m x 4c.
__global__ void k_pv(const float* __restrict__ q, const float* __restrict__ k,
                     const float* __restrict__ v, const float* __restrict__ rowmax,
                     const float* __restrict__ rowinv, float* __restrict__ xr) {
    __shared__ float ks[32][36];
    __shared__ float qs[64][36];
    __shared__ float vs[64][CC];
    __shared__ float as[64][36];
    __shared__ float rmx[64], rin[64];
    int b = blockIdx.x >> 6;
    int m0 = (blockIdx.x & 63) * 32;
    int t = threadIdx.x;
    // stage K rows for this m-tile: 1024 floats = 256 float4
    {
        const float4* kb = (const float4*)(k + ((long)b * NN + m0) * DD);
        float4 tv = kb[t];
        int r = t >> 3, c = (t & 7) * 4;
        *(float4*)&ks[r][c] = tv;
    }
    int mg = t >> 5;        // 0..7 -> 4 m's each
    int cg = t & 31;        // 0..31 -> 4 c's each
    float acc[4][4];
    #pragma unroll
    for (int i = 0; i < 4; ++i)
        #pragma unroll
        for (int j = 0; j < 4; ++j) acc[i][j] = 0.f;
    for (int nt = 0; nt < NN; nt += 64) {
        __syncthreads();
        const float4* qb = (const float4*)(q + ((long)b * NN + nt) * DD);
        #pragma unroll
        for (int rep = 0; rep < 2; ++rep) {
            int i = rep * BDIM + t;           // 512 float4
            int r = i >> 3, c = (i & 7) * 4;
            *(float4*)&qs[r][c] = qb[i];
        }
        const float4* vb = (const float4*)(v + ((long)b * NN + nt) * CC);
        float4* vs4 = (float4*)&vs[0][0];
        #pragma unroll
        for (int rep = 0; rep < 8; ++rep) vs4[rep * BDIM + t] = vb[rep * BDIM + t];
        if (t < 64) rmx[t] = rowmax[(long)b * NN + nt + t];
        else if (t < 128) rin[t - 64] = rowinv[(long)b * NN + nt + (t - 64)];
        __syncthreads();
        // energy tile 64n x 32m
        #pragma unroll
        for (int rep = 0; rep < 8; ++rep) {
            int id = rep * BDIM + t;
            int n = id >> 5, m = id & 31;
            const float4* qv = (const float4*)&qs[n][0];
            const float4* kv = (const float4*)&ks[m][0];
            float e = 0.f;
            #pragma unroll
            for (int j = 0; j < 8; ++j) {
                float4 a = qv[j], w = kv[j];
                e += a.x * w.x + a.y * w.y + a.z * w.z + a.w * w.w;
            }
            as[n][m] = __expf(e * SCALE - rmx[n]) * rin[n];
        }
        __syncthreads();
        #pragma unroll 4
        for (int n = 0; n < 64; ++n) {
            float4 a4 = *(const float4*)&as[n][mg * 4];
            float4 v4 = *(const float4*)&vs[n][cg * 4];
            const float* ap = (const float*)&a4;
            #pragma unroll
            for (int mi = 0; mi < 4; ++mi) {
                float a = ap[mi];
                acc[mi][0] += a * v4.x; acc[mi][1] += a * v4.y;
                acc[mi][2] += a * v4.z; acc[mi][3] += a * v4.w;
            }
        }
    }
    #pragma unroll
    for (int mi = 0; mi < 4; ++mi) {
        int m = m0 + mg * 4 + mi;
        float* o = xr + ((long)b * NN + m) * CC + cg * 4;
        *(float4*)o = make_float4(acc[mi][0], acc[mi][1], acc[mi][2], acc[mi][3]);
    }
}

// ---------------- kernel 4: h = bf16(x + relu(BN1(Wt (x - xr) + bt))) ----------------
__global__ void k_tproj(const float* __restrict__ x, const float* __restrict__ xr,
                        const float* __restrict__ Wt, const float* __restrict__ bt,
                        const float* __restrict__ g1, const float* __restrict__ b1,
                        const float* __restrict__ m1, const float* __restrict__ v1,
                        ushort_t* __restrict__ hb) {
    __shared__ float ds[16][CC];
    long base = (long)blockIdx.x * 16;
    const float4* xg = (const float4*)(x + base * CC);
    const float4* rg = (const float4*)(xr + base * CC);
    float4* ds4 = (float4*)&ds[0][0];
    for (int i = threadIdx.x; i < 16 * (CC / 4); i += BDIM) {
        float4 a = xg[i], r = rg[i];
        ds4[i] = make_float4(a.x - r.x, a.y - r.y, a.z - r.z, a.w - r.w);
    }
    __syncthreads();
    for (int rep = 0; rep < 8; ++rep) {
        int id = rep * BDIM + threadIdx.x;
        int p = id >> 7, o = id & 127;
        const float4* w4 = (const float4*)(Wt + o * CC);
        const float4* d4 = (const float4*)&ds[p][0];
        float s = bt[o];
        #pragma unroll
        for (int j = 0; j < CC / 4; ++j) {
            float4 a = d4[j], w = w4[j];
            s += a.x * w.x + a.y * w.y + a.z * w.z + a.w * w.w;
        }
        float sc = g1[o] * rsqrtf(v1[o] + 1e-5f);
        float tv = (s - m1[o]) * sc + b1[o];
        tv = fmaxf(tv, 0.f);
        hb[(base + p) * CC + o] = bf16r(x[(base + p) * CC + o] + tv);
    }
}

// ---------------- kernel 5: MFMA fused FF ----------------
// out = BN2(h + W2 relu(W1 h + bf1) + bf2). 32 points/block, 512 blocks, 4 waves.
__global__ __launch_bounds__(256) void k_ff(
        const ushort_t* __restrict__ hb, const ushort_t* __restrict__ W1b,
        const ushort_t* __restrict__ W2b,
        const float* __restrict__ bf1, const float* __restrict__ bf2,
        const float* __restrict__ g2, const float* __restrict__ b2,
        const float* __restrict__ m2, const float* __restrict__ v2,
        float* __restrict__ out) {
    __shared__ ushort_t hs[32][136];    // h tile (bf16), +8 pad
    __shared__ ushort_t w1s[64][136];   // W1 f-chunk rows
    __shared__ ushort_t w2s[128][72];   // W2 cols f-chunk
    __shared__ ushort_t fss[32][72];    // fs chunk
    long pbase = (long)blockIdx.x * 32;
    int t = threadIdx.x;
    // stage h tile: 4096 halves = 512 x 16B
    for (int i = t; i < 512; i += BDIM) {
        int r = i >> 4, c0 = (i & 15) * 8;
        *(uint4*)&hs[r][c0] = *(const uint4*)(hb + (pbase + r) * CC + c0);
    }
    __syncthreads();
    int l = t & 63, wid = t >> 6;
    int ph = wid & 1;          // p-half (16 rows)
    int fh = wid >> 1;         // f/o split
    int lr = l & 15, lg = l >> 4;
    // preload A-frags (h rows) once: K=128 -> 4 frags
    s16x8 hA[4];
    #pragma unroll
    for (int ki = 0; ki < 4; ++ki)
        hA[ki] = *(const s16x8*)&hs[ph * 16 + lr][ki * 32 + lg * 8];
    f32x4 acc2[4];
    #pragma unroll
    for (int i = 0; i < 4; ++i) acc2[i] = (f32x4){0.f, 0.f, 0.f, 0.f};

    for (int fc = 0; fc < 8; ++fc) {
        int f0 = fc * 64;
        __syncthreads();
        // stage W1 chunk: 64 rows x 128 halves = 1024 x 16B
        for (int i = t; i < 1024; i += BDIM) {
            int r = i >> 4, c0 = (i & 15) * 8;
            *(uint4*)&w1s[r][c0] = *(const uint4*)(W1b + (f0 + r) * CC + c0);
        }
        // stage W2 chunk: 128 rows x 64 halves = 1024 x 16B
        for (int i = t; i < 1024; i += BDIM) {
            int r = i >> 3, c0 = (i & 7) * 8;
            *(uint4*)&w2s[r][c0] = *(const uint4*)(W2b + r * FF + f0 + c0);
        }
        __syncthreads();
        // phase 1: fs chunk = relu(h.W1^T + bf1)
        #pragma unroll
        for (int fi = 0; fi < 2; ++fi) {
            int ft = fh * 2 + fi;
            f32x4 a1 = (f32x4){0.f, 0.f, 0.f, 0.f};
            #pragma unroll
            for (int ki = 0; ki < 4; ++ki) {
                s16x8 bfr = *(const s16x8*)&w1s[ft * 16 + lr][ki * 32 + lg * 8];
                a1 = __builtin_amdgcn_mfma_f32_16x16x32_bf16(hA[ki], bfr, a1, 0, 0, 0);
            }
            float bias = bf1[f0 + ft * 16 + lr];
            #pragma unroll
            for (int r = 0; r < 4; ++r) {
                float vv = fmaxf(a1[r] + bias, 0.f);
                fss[ph * 16 + lg * 4 + r][ft * 16 + lr] = bf16r(vv);
            }
        }
        __syncthreads();
        // phase 2: acc2 += fs_chunk . W2_chunk^T
        #pragma unroll
        for (int k2 = 0; k2 < 2; ++k2) {
            s16x8 afr = *(const s16x8*)&fss[ph * 16 + lr][k2 * 32 + lg * 8];
            #pragma unroll
            for (int oi = 0; oi < 4; ++oi) {
                int ot = fh * 4 + oi;
                s16x8 bfr = *(const s16x8*)&w2s[ot * 16 + lr][k2 * 32 + lg * 8];
                acc2[oi] = __builtin_amdgcn_mfma_f32_16x16x32_bf16(afr, bfr, acc2[oi], 0, 0, 0);
            }
        }
    }
    // epilogue: out = BN2(h + acc2 + bf2)
    #pragma unroll
    for (int oi = 0; oi < 4; ++oi) {
        int o = (fh * 4 + oi) * 16 + lr;
        float sc = g2[o] * rsqrtf(v2[o] + 1e-5f);
        float mm = m2[o], bb = b2[o], bias2 = bf2[o];
        #pragma unroll
        for (int r = 0; r < 4; ++r) {
            int p = ph * 16 + lg * 4 + r;
            float val = bf16tof(hs[p][o]) + acc2[oi][r] + bias2;
            out[(pbase + p) * CC + o] = (val - mm) * sc + bb;
        }
    }
}

extern "C" void kernel_launch(void* const* d_in, const int* in_sizes, int n_in,
                              void* d_out, int out_size, void* d_ws, size_t ws_size,
                              hipStream_t stream) {
    const float* x   = (const float*)d_in[0];
    const float* Wq  = (const float*)d_in[1];
    const float* Wk  = (const float*)d_in[2];
    const float* Wv  = (const float*)d_in[3];
    const float* bv  = (const float*)d_in[4];
    const float* Wt  = (const float*)d_in[5];
    const float* bt  = (const float*)d_in[6];
    const float* g1  = (const float*)d_in[7];
    const float* b1  = (const float*)d_in[8];
    const float* m1  = (const float*)d_in[9];
    const float* v1  = (const float*)d_in[10];
    const float* W1  = (const float*)d_in[11];
    const float* bf1 = (const float*)d_in[12];
    const float* W2  = (const float*)d_in[13];
    const float* bf2 = (const float*)d_in[14];
    const float* g2  = (const float*)d_in[15];
    const float* b2  = (const float*)d_in[16];
    const float* m2  = (const float*)d_in[17];
    const float* v2  = (const float*)d_in[18];
    float* out = (float*)d_out;

    float* ws  = (float*)d_ws;
    float* q   = ws;                       // NPTS*32
    float* k   = q + (long)NPTS * DD;      // NPTS*32
    float* v   = k + (long)NPTS * DD;      // NPTS*128
    float* xr  = v + (long)NPTS * CC;      // NPTS*128
    float* rmx = xr + (long)NPTS * CC;     // NPTS
    float* rin = rmx + NPTS;               // NPTS
    ushort_t* hbuf = (ushort_t*)(rin + NPTS);   // NPTS*128 bf16
    ushort_t* W1b  = hbuf + (long)NPTS * CC;    // 65536 bf16
    ushort_t* W2b  = W1b + FF * CC;             // 65536 bf16

    k_cvt<<<FF * CC / 4 / BDIM, BDIM, 0, stream>>>(W1, W1b, FF * CC / 4);
    k_cvt<<<FF * CC / 4 / BDIM, BDIM, 0, stream>>>(W2, W2b, FF * CC / 4);
    k_proj<<<NPTS / 16, BDIM, 0, stream>>>(x, Wq, Wk, Wv, bv, q, k, v);
    k_rowstats<<<8 * (NN / 32), BDIM, 0, stream>>>(q, k, rmx, rin);
    k_pv<<<8 * (NN / 32), BDIM, 0, stream>>>(q, k, v, rmx, rin, xr);
    k_tproj<<<NPTS / 16, BDIM, 0, stream>>>(x, xr, Wt, bt, g1, b1, m1, v1, hbuf);
    k_ff<<<NPTS / 32, BDIM, 0, stream>>>(hbuf, W1b, W2b, bf1, bf2, g2, b2, m2, v2, out);
}

// Round 4
// 497.619 us; speedup vs baseline: 5.5365x; 2.0837x over previous
//
#include <hip/hip_runtime.h>
#include <hip/hip_bf16.h>

#define BDIM 256
#define NPTS (8 * 2048)           // B*N
#define CC 128
#define DD 32
#define FF 512
#define NN 2048
#define SCALE 0.08838834764831845f   // 1/sqrt(128)

typedef float f32x4 __attribute__((ext_vector_type(4)));
typedef short s16x8 __attribute__((ext_vector_type(8)));
typedef unsigned short ushort_t;

__device__ __forceinline__ ushort_t bf16r(float x) {
    __hip_bfloat16 h = __float2bfloat16(x);
    return *reinterpret_cast<ushort_t*>(&h);
}
__device__ __forceinline__ float bf16tof(ushort_t u) {
    unsigned v = ((unsigned)u) << 16;
    return *reinterpret_cast<float*>(&v);
}
__device__ __forceinline__ unsigned pack2(float a, float b) {
    return ((unsigned)bf16r(b) << 16) | (unsigned)bf16r(a);
}
__device__ __forceinline__ float dot128(const float4* __restrict__ a,
                                        const float* __restrict__ w) {
    const float4* w4 = (const float4*)w;
    float s = 0.f;
    #pragma unroll
    for (int j = 0; j < 32; ++j) {
        float4 p = a[j], q = w4[j];
        s += p.x * q.x + p.y * q.y + p.z * q.z + p.w * q.w;
    }
    return s;
}

// ---------------- kernel 0: f32 -> bf16 weight conversion ----------------
__global__ void k_cvt(const float* __restrict__ a, ushort_t* __restrict__ o, int n4) {
    int i = blockIdx.x * BDIM + threadIdx.x;
    if (i < n4) {
        float4 v = ((const float4*)a)[i];
        o[i*4+0] = bf16r(v.x); o[i*4+1] = bf16r(v.y);
        o[i*4+2] = bf16r(v.z); o[i*4+3] = bf16r(v.w);
    }
}

// ---------------- kernel 1: q/k bf16 [n][32], vT bf16 [b][c][n] ----------------
__global__ __launch_bounds__(256) void k_proj(
        const float* __restrict__ x, const float* __restrict__ Wq,
        const float* __restrict__ Wk, const float* __restrict__ Wv,
        const float* __restrict__ bv,
        ushort_t* __restrict__ qg, ushort_t* __restrict__ kg,
        ushort_t* __restrict__ vTg) {
    __shared__ float xs[16][CC];
    __shared__ ushort_t vs[16][136];
    long base = (long)blockIdx.x * 16;
    int b = (int)(base >> 11);          // /NN
    int n0 = (int)(base & (NN - 1));
    int t = threadIdx.x;
    const float4* xg = (const float4*)(x + base * CC);
    float4* xs4 = (float4*)&xs[0][0];
    for (int i = t; i < 16 * (CC / 4); i += BDIM) xs4[i] = xg[i];
    __syncthreads();
    // q, k: one oc-pair per thread (16 p x 16 pairs)
    {
        int p = t >> 4, pr = t & 15;
        const float4* xp = (const float4*)&xs[p][0];
        float s0 = dot128(xp, Wq + (2*pr) * CC);
        float s1 = dot128(xp, Wq + (2*pr+1) * CC);
        *(unsigned*)(qg + (base + p) * DD + 2*pr) = pack2(s0, s1);
        s0 = dot128(xp, Wk + (2*pr) * CC);
        s1 = dot128(xp, Wk + (2*pr+1) * CC);
        *(unsigned*)(kg + (base + p) * DD + 2*pr) = pack2(s0, s1);
    }
    // v -> LDS (bf16), 4 reps of (16p x 64 c-pairs)
    for (int rep = 0; rep < 4; ++rep) {
        int id = rep * BDIM + t;
        int p = id >> 6, c = (id & 63) * 2;
        const float4* xp = (const float4*)&xs[p][0];
        float s0 = dot128(xp, Wv + c * CC) + bv[c];
        float s1 = dot128(xp, Wv + (c+1) * CC) + bv[c+1];
        *(unsigned*)&vs[p][c] = pack2(s0, s1);
    }
    __syncthreads();
    // transposed write-out: thread -> (c, n-half of 8)
    {
        int c = t >> 1, h = t & 1;
        uint4 r;
        r.x = (unsigned)vs[8*h+0][c] | ((unsigned)vs[8*h+1][c] << 16);
        r.y = (unsigned)vs[8*h+2][c] | ((unsigned)vs[8*h+3][c] << 16);
        r.z = (unsigned)vs[8*h+4][c] | ((unsigned)vs[8*h+5][c] << 16);
        r.w = (unsigned)vs[8*h+6][c] | ((unsigned)vs[8*h+7][c] << 16);
        *(uint4*)(vTg + ((long)(b * CC + c)) * NN + n0 + 8*h) = r;
    }
}

// ---------------- kernel 2: MFMA row softmax stats ----------------
// grid: 8 b x 64 n-tiles(32) = 512 blocks. Waves split m-space; LDS merge.
__global__ __launch_bounds__(256) void k_rowstats(
        const ushort_t* __restrict__ qg, const ushort_t* __restrict__ kg,
        float* __restrict__ rowmax, float* __restrict__ rowinv) {
    __shared__ float pm[4][32], ps[4][32];
    int b = blockIdx.x >> 6;
    int nt = (blockIdx.x & 63) * 32;
    int t = threadIdx.x, w = t >> 6, l = t & 63, a = l & 15, g = l >> 4;
    s16x8 qA[2];
    #pragma unroll
    for (int s = 0; s < 2; ++s)
        qA[s] = *(const s16x8*)(qg + ((long)(b * NN + nt + s*16 + a)) * DD + g*8);
    float mx[8], sm[8];
    #pragma unroll
    for (int i = 0; i < 8; ++i) { mx[i] = -1e30f; sm[i] = 0.f; }
    for (int it = 0; it < 32; ++it) {
        int m0 = (it * 4 + w) * 16;
        s16x8 kB = *(const s16x8*)(kg + ((long)(b * NN + m0 + a)) * DD + g*8);
        #pragma unroll
        for (int s = 0; s < 2; ++s) {
            f32x4 D = (f32x4){0.f, 0.f, 0.f, 0.f};
            D = __builtin_amdgcn_mfma_f32_16x16x32_bf16(qA[s], kB, D, 0, 0, 0);
            #pragma unroll
            for (int r = 0; r < 4; ++r) {
                float e = D[r] * SCALE;
                int ix = s * 4 + r;
                float nm = fmaxf(mx[ix], e);
                sm[ix] = sm[ix] * __expf(mx[ix] - nm) + __expf(e - nm);
                mx[ix] = nm;
            }
        }
    }
    // reduce across the 16 lanes (a) sharing the same n-set
    #pragma unroll
    for (int off = 1; off < 16; off <<= 1) {
        #pragma unroll
        for (int ix = 0; ix < 8; ++ix) {
            float omx = __shfl_xor(mx[ix], off, 64);
            float osm = __shfl_xor(sm[ix], off, 64);
            float nm = fmaxf(mx[ix], omx);
            sm[ix] = sm[ix] * __expf(mx[ix] - nm) + osm * __expf(omx - nm);
            mx[ix] = nm;
        }
    }
    // per-wave partials -> LDS (each wave covered only 1/4 of m-space)
    if (a == 0) {
        #pragma unroll
        for (int s = 0; s < 2; ++s)
            #pragma unroll
            for (int r = 0; r < 4; ++r) {
                pm[w][s * 16 + g * 4 + r] = mx[s * 4 + r];
                ps[w][s * 16 + g * 4 + r] = sm[s * 4 + r];
            }
    }
    __syncthreads();
    // merge the 4 wave partials per n and write final stats
    if (t < 32) {
        float m0 = pm[0][t], m1 = pm[1][t], m2 = pm[2][t], m3 = pm[3][t];
        float M = fmaxf(fmaxf(m0, m1), fmaxf(m2, m3));
        float S = ps[0][t] * __expf(m0 - M) + ps[1][t] * __expf(m1 - M)
                + ps[2][t] * __expf(m2 - M) + ps[3][t] * __expf(m3 - M);
        rowmax[(long)b * NN + nt + t] = M;
        rowinv[(long)b * NN + nt + t] = 1.f / S;
    }
}

// ---------------- kernel 3: MFMA PV: xr[m][c] = sum_n P[n][m] v[n][c] ----------------
// grid: 8 b x 64 m-tiles(32) = 512 blocks, 4 waves.
__global__ __launch_bounds__(256) void k_pv(
        const ushort_t* __restrict__ qg, const ushort_t* __restrict__ kg,
        const ushort_t* __restrict__ vTg,
        const float* __restrict__ rowmax, const float* __restrict__ rowinv,
        float* __restrict__ xr) {
    __shared__ ushort_t qs[64][40];     // 80B rows (16B aligned)
    __shared__ ushort_t ks[32][40];
    __shared__ ushort_t vTs[128][72];   // 144B rows
    __shared__ ushort_t pT[32][72];
    __shared__ float rmx_s[64], rin_s[64];
    int b = blockIdx.x >> 6;
    int m0 = (blockIdx.x & 63) * 32;
    int t = threadIdx.x, w = t >> 6, l = t & 63, a = l & 15, g = l >> 4;
    // stage K tile once (32 rows x 32 d)
    if (t < 128) {
        int r = t >> 2, o = (t & 3) * 8;
        *(s16x8*)&ks[r][o] = *(const s16x8*)(kg + ((long)(b * NN + m0 + r)) * DD + o);
    }
    f32x4 acc[2][2];
    #pragma unroll
    for (int i = 0; i < 2; ++i)
        #pragma unroll
        for (int j = 0; j < 2; ++j) acc[i][j] = (f32x4){0.f, 0.f, 0.f, 0.f};
    const ushort_t* vTb = vTg + (long)b * CC * NN;
    for (int nt = 0; nt < NN; nt += 64) {
        __syncthreads();
        // stage Q tile 64x32
        {
            int r = t >> 2, o = (t & 3) * 8;
            *(s16x8*)&qs[r][o] = *(const s16x8*)(qg + ((long)(b * NN + nt + r)) * DD + o);
        }
        // stage vT tile 128c x 64n
        #pragma unroll
        for (int rep = 0; rep < 4; ++rep) {
            int lin = rep * BDIM + t;
            int c = lin >> 3, o = (lin & 7) * 8;
            *(s16x8*)&vTs[c][o] = *(const s16x8*)(vTb + (long)c * NN + nt + o);
        }
        if (t < 64) rmx_s[t] = rowmax[(long)b * NN + nt + t];
        else if (t < 128) rin_s[t - 64] = rowinv[(long)b * NN + nt + (t - 64)];
        __syncthreads();
        // E: wave w handles n-sub w (16 n) x both m-subs
        f32x4 e0 = (f32x4){0.f, 0.f, 0.f, 0.f}, e1 = e0;
        s16x8 qf = *(const s16x8*)&qs[w * 16 + a][g * 8];
        e0 = __builtin_amdgcn_mfma_f32_16x16x32_bf16(qf, *(const s16x8*)&ks[a][g * 8], e0, 0, 0, 0);
        e1 = __builtin_amdgcn_mfma_f32_16x16x32_bf16(qf, *(const s16x8*)&ks[16 + a][g * 8], e1, 0, 0, 0);
        float p0[4], p1[4];
        #pragma unroll
        for (int r = 0; r < 4; ++r) {
            int n = w * 16 + g * 4 + r;
            float RM = rmx_s[n], RI = rin_s[n];
            p0[r] = __expf(e0[r] * SCALE - RM) * RI;
            p1[r] = __expf(e1[r] * SCALE - RM) * RI;
        }
        {
            uint2 u0 = make_uint2(pack2(p0[0], p0[1]), pack2(p0[2], p0[3]));
            uint2 u1 = make_uint2(pack2(p1[0], p1[1]), pack2(p1[2], p1[3]));
            *(uint2*)&pT[a][w * 16 + g * 4] = u0;
            *(uint2*)&pT[16 + a][w * 16 + g * 4] = u1;
        }
        __syncthreads();
        // PV: wave w -> c-quarter w
        #pragma unroll
        for (int k2 = 0; k2 < 2; ++k2) {
            s16x8 A0 = *(const s16x8*)&pT[a][k2 * 32 + g * 8];
            s16x8 A1 = *(const s16x8*)&pT[16 + a][k2 * 32 + g * 8];
            s16x8 B0 = *(const s16x8*)&vTs[w * 32 + a][k2 * 32 + g * 8];
            s16x8 B1 = *(const s16x8*)&vTs[w * 32 + 16 + a][k2 * 32 + g * 8];
            acc[0][0] = __builtin_amdgcn_mfma_f32_16x16x32_bf16(A0, B0, acc[0][0], 0, 0, 0);
            acc[0][1] = __builtin_amdgcn_mfma_f32_16x16x32_bf16(A0, B1, acc[0][1], 0, 0, 0);
            acc[1][0] = __builtin_amdgcn_mfma_f32_16x16x32_bf16(A1, B0, acc[1][0], 0, 0, 0);
            acc[1][1] = __builtin_amdgcn_mfma_f32_16x16x32_bf16(A1, B1, acc[1][1], 0, 0, 0);
        }
    }
    #pragma unroll
    for (int ms = 0; ms < 2; ++ms)
        #pragma unroll
        for (int cs = 0; cs < 2; ++cs)
            #pragma unroll
            for (int r = 0; r < 4; ++r) {
                int m = m0 + ms * 16 + g * 4 + r;
                int c = w * 32 + cs * 16 + a;
                xr[((long)b * NN + m) * CC + c] = acc[ms][cs][r];
            }
}

// ---------------- kernel 4: h = bf16(x + relu(BN1(Wt (x - xr) + bt))) ----------------
__global__ void k_tproj(const float* __restrict__ x, const float* __restrict__ xr,
                        const float* __restrict__ Wt, const float* __restrict__ bt,
                        const float* __restrict__ g1, const float* __restrict__ b1,
                        const float* __restrict__ m1, const float* __restrict__ v1,
                        ushort_t* __restrict__ hb) {
    __shared__ float ds[16][CC];
    long base = (long)blockIdx.x * 16;
    const float4* xg = (const float4*)(x + base * CC);
    const float4* rg = (const float4*)(xr + base * CC);
    float4* ds4 = (float4*)&ds[0][0];
    for (int i = threadIdx.x; i < 16 * (CC / 4); i += BDIM) {
        float4 a = xg[i], r = rg[i];
        ds4[i] = make_float4(a.x - r.x, a.y - r.y, a.z - r.z, a.w - r.w);
    }
    __syncthreads();
    for (int rep = 0; rep < 8; ++rep) {
        int id = rep * BDIM + threadIdx.x;
        int p = id >> 7, o = id & 127;
        const float4* d4 = (const float4*)&ds[p][0];
        float s = bt[o] + dot128(d4, Wt + o * CC);
        float sc = g1[o] * rsqrtf(v1[o] + 1e-5f);
        float tv = (s - m1[o]) * sc + b1[o];
        tv = fmaxf(tv, 0.f);
        hb[(base + p) * CC + o] = bf16r(x[(base + p) * CC + o] + tv);
    }
}

// ---------------- kernel 5: MFMA fused FF ----------------
__global__ __launch_bounds__(256) void k_ff(
        const ushort_t* __restrict__ hb, const ushort_t* __restrict__ W1b,
        const ushort_t* __restrict__ W2b,
        const float* __restrict__ bf1, const float* __restrict__ bf2,
        const float* __restrict__ g2, const float* __restrict__ b2,
        const float* __restrict__ m2, const float* __restrict__ v2,
        float* __restrict__ out) {
    __shared__ ushort_t hs[32][136];
    __shared__ ushort_t w1s[64][136];
    __shared__ ushort_t w2s[128][72];
    __shared__ ushort_t fss[32][72];
    long pbase = (long)blockIdx.x * 32;
    int t = threadIdx.x;
    for (int i = t; i < 512; i += BDIM) {
        int r = i >> 4, c0 = (i & 15) * 8;
        *(uint4*)&hs[r][c0] = *(const uint4*)(hb + (pbase + r) * CC + c0);
    }
    __syncthreads();
    int l = t & 63, wid = t >> 6;
    int ph = wid & 1;
    int fh = wid >> 1;
    int lr = l & 15, lg = l >> 4;
    s16x8 hA[4];
    #pragma unroll
    for (int ki = 0; ki < 4; ++ki)
        hA[ki] = *(const s16x8*)&hs[ph * 16 + lr][ki * 32 + lg * 8];
    f32x4 acc2[4];
    #pragma unroll
    for (int i = 0; i < 4; ++i) acc2[i] = (f32x4){0.f, 0.f, 0.f, 0.f};

    for (int fc = 0; fc < 8; ++fc) {
        int f0 = fc * 64;
        __syncthreads();
        for (int i = t; i < 1024; i += BDIM) {
            int r = i >> 4, c0 = (i & 15) * 8;
            *(uint4*)&w1s[r][c0] = *(const uint4*)(W1b + (f0 + r) * CC + c0);
        }
        for (int i = t; i < 1024; i += BDIM) {
            int r = i >> 3, c0 = (i & 7) * 8;
            *(uint4*)&w2s[r][c0] = *(const uint4*)(W2b + r * FF + f0 + c0);
        }
        __syncthreads();
        #pragma unroll
        for (int fi = 0; fi < 2; ++fi) {
            int ft = fh * 2 + fi;
            f32x4 a1 = (f32x4){0.f, 0.f, 0.f, 0.f};
            #pragma unroll
            for (int ki = 0; ki < 4; ++ki) {
                s16x8 bfr = *(const s16x8*)&w1s[ft * 16 + lr][ki * 32 + lg * 8];
                a1 = __builtin_amdgcn_mfma_f32_16x16x32_bf16(hA[ki], bfr, a1, 0, 0, 0);
            }
            float bias = bf1[f0 + ft * 16 + lr];
            #pragma unroll
            for (int r = 0; r < 4; ++r) {
                float vv = fmaxf(a1[r] + bias, 0.f);
                fss[ph * 16 + lg * 4 + r][ft * 16 + lr] = bf16r(vv);
            }
        }
        __syncthreads();
        #pragma unroll
        for (int k2 = 0; k2 < 2; ++k2) {
            s16x8 afr = *(const s16x8*)&fss[ph * 16 + lr][k2 * 32 + lg * 8];
            #pragma unroll
            for (int oi = 0; oi < 4; ++oi) {
                int ot = fh * 4 + oi;
                s16x8 bfr = *(const s16x8*)&w2s[ot * 16 + lr][k2 * 32 + lg * 8];
                acc2[oi] = __builtin_amdgcn_mfma_f32_16x16x32_bf16(afr, bfr, acc2[oi], 0, 0, 0);
            }
        }
    }
    #pragma unroll
    for (int oi = 0; oi < 4; ++oi) {
        int o = (fh * 4 + oi) * 16 + lr;
        float sc = g2[o] * rsqrtf(v2[o] + 1e-5f);
        float mm = m2[o], bb = b2[o], bias2 = bf2[o];
        #pragma unroll
        for (int r = 0; r < 4; ++r) {
            int p = ph * 16 + lg * 4 + r;
            float val = bf16tof(hs[p][o]) + acc2[oi][r] + bias2;
            out[(pbase + p) * CC + o] = (val - mm) * sc + bb;
        }
    }
}

extern "C" void kernel_launch(void* const* d_in, const int* in_sizes, int n_in,
                              void* d_out, int out_size, void* d_ws, size_t ws_size,
                              hipStream_t stream) {
    const float* x   = (const float*)d_in[0];
    const float* Wq  = (const float*)d_in[1];
    const float* Wk  = (const float*)d_in[2];
    const float* Wv  = (const float*)d_in[3];
    const float* bv  = (const float*)d_in[4];
    const float* Wt  = (const float*)d_in[5];
    const float* bt  = (const float*)d_in[6];
    const float* g1  = (const float*)d_in[7];
    const float* b1  = (const float*)d_in[8];
    const float* m1  = (const float*)d_in[9];
    const float* v1  = (const float*)d_in[10];
    const float* W1  = (const float*)d_in[11];
    const float* bf1 = (const float*)d_in[12];
    const float* W2  = (const float*)d_in[13];
    const float* bf2 = (const float*)d_in[14];
    const float* g2  = (const float*)d_in[15];
    const float* b2  = (const float*)d_in[16];
    const float* m2  = (const float*)d_in[17];
    const float* v2  = (const float*)d_in[18];
    float* out = (float*)d_out;

    float* ws  = (float*)d_ws;
    float* xr  = ws;                            // NPTS*CC f32
    float* rmx = xr + (long)NPTS * CC;          // NPTS
    float* rin = rmx + NPTS;                    // NPTS
    ushort_t* qg   = (ushort_t*)(rin + NPTS);   // NPTS*DD bf16
    ushort_t* kg   = qg + (long)NPTS * DD;      // NPTS*DD
    ushort_t* vTg  = kg + (long)NPTS * DD;      // NPTS*CC ([b][c][n])
    ushort_t* hbuf = vTg + (long)NPTS * CC;     // NPTS*CC
    ushort_t* W1b  = hbuf + (long)NPTS * CC;    // FF*CC
    ushort_t* W2b  = W1b + FF * CC;             // FF*CC

    k_cvt<<<FF * CC / 4 / BDIM, BDIM, 0, stream>>>(W1, W1b, FF * CC / 4);
    k_cvt<<<FF * CC / 4 / BDIM, BDIM, 0, stream>>>(W2, W2b, FF * CC / 4);
    k_proj<<<NPTS / 16, BDIM, 0, stream>>>(x, Wq, Wk, Wv, bv, qg, kg, vTg);
    k_rowstats<<<8 * (NN / 32), BDIM, 0, stream>>>(qg, kg, rmx, rin);
    k_pv<<<8 * (NN / 32), BDIM, 0, stream>>>(qg, kg, vTg, rmx, rin, xr);
    k_tproj<<<NPTS / 16, BDIM, 0, stream>>>(x, xr, Wt, bt, g1, b1, m1, v1, hbuf);
    k_ff<<<NPTS / 32, BDIM, 0, stream>>>(hbuf, W1b, W2b, bf1, bf2, g2, b2, m2, v2, out);
}

// Round 6
// 126.157 us; speedup vs baseline: 21.8384x; 3.9444x over previous
//
#include <hip/hip_runtime.h>
#include <hip/hip_bf16.h>

#define BDIM 256
#define NPTS (8 * 2048)           // B*N
#define CC 128
#define DD 32
#define FF 512
#define NN 2048
#define SCALE 0.08838834764831845f   // 1/sqrt(128)

typedef float f32x4 __attribute__((ext_vector_type(4)));
typedef short s16x8 __attribute__((ext_vector_type(8)));
typedef unsigned short ushort_t;

__device__ __forceinline__ ushort_t bf16r(float x) {
    __hip_bfloat16 h = __float2bfloat16(x);
    return *reinterpret_cast<ushort_t*>(&h);
}
__device__ __forceinline__ float bf16tof(ushort_t u) {
    unsigned v = ((unsigned)u) << 16;
    return *reinterpret_cast<float*>(&v);
}
__device__ __forceinline__ unsigned pack2(float a, float b) {
    return ((unsigned)bf16r(b) << 16) | (unsigned)bf16r(a);
}

// ---------------- kernel 0: f32 -> bf16 conversion ----------------
__global__ void k_cvt(const float* __restrict__ a, ushort_t* __restrict__ o, int n4) {
    int i = blockIdx.x * BDIM + threadIdx.x;
    if (i < n4) {
        float4 v = ((const float4*)a)[i];
        o[i*4+0] = bf16r(v.x); o[i*4+1] = bf16r(v.y);
        o[i*4+2] = bf16r(v.z); o[i*4+3] = bf16r(v.w);
    }
}

// ---------------- kernel 1: MFMA q/k/vT projection ----------------
// grid: NPTS/64 blocks. Wb = packed [192][128] bf16 (Wq|Wk|Wv).
// outputs: q,k bf16 [n][32]; vT bf16 [b][c][n].
__global__ __launch_bounds__(256) void k_proj(
        const float* __restrict__ x, const ushort_t* __restrict__ Wb,
        const float* __restrict__ bv,
        ushort_t* __restrict__ qg, ushort_t* __restrict__ kg,
        ushort_t* __restrict__ vTg) {
    __shared__ ushort_t xs[64][136];
    __shared__ ushort_t qks[64][72];    // q cols 0-31, k cols 32-63
    __shared__ ushort_t vs[64][136];
    long base = (long)blockIdx.x * 64;
    int b = (int)(base >> 11);
    int n0 = (int)(base & (NN - 1));
    int t = threadIdx.x, w = t >> 6, l = t & 63, a = l & 15, g = l >> 4;
    // stage x tile as bf16: 2048 float4
    {
        const float4* xg4 = (const float4*)(x + base * CC);
        #pragma unroll
        for (int rep = 0; rep < 8; ++rep) {
            int i = rep * BDIM + t;
            float4 v4 = xg4[i];
            int p = i >> 5, c4 = (i & 31) * 4;
            *(uint2*)&xs[p][c4] = make_uint2(pack2(v4.x, v4.y), pack2(v4.z, v4.w));
        }
    }
    // B-frags: wave w owns col-tiles 3w..3w+2 (oc = ctg*16 + a)
    s16x8 bF[3][4];
    #pragma unroll
    for (int ct = 0; ct < 3; ++ct) {
        int ctg = w * 3 + ct;
        #pragma unroll
        for (int ki = 0; ki < 4; ++ki)
            bF[ct][ki] = *(const s16x8*)(Wb + ((long)(ctg * 16 + a)) * CC + ki * 32 + g * 8);
    }
    __syncthreads();
    // 4 row-tiles of 16 points each
    #pragma unroll
    for (int rt = 0; rt < 4; ++rt) {
        s16x8 aF[4];
        #pragma unroll
        for (int ki = 0; ki < 4; ++ki)
            aF[ki] = *(const s16x8*)&xs[rt * 16 + a][ki * 32 + g * 8];
        #pragma unroll
        for (int ct = 0; ct < 3; ++ct) {
            f32x4 acc = (f32x4){0.f, 0.f, 0.f, 0.f};
            #pragma unroll
            for (int ki = 0; ki < 4; ++ki)
                acc = __builtin_amdgcn_mfma_f32_16x16x32_bf16(aF[ki], bF[ct][ki], acc, 0, 0, 0);
            int ctg = w * 3 + ct;
            int oc = ctg * 16 + a;
            float bias = (oc >= 64) ? bv[oc - 64] : 0.f;
            #pragma unroll
            for (int r = 0; r < 4; ++r) {
                int p = rt * 16 + g * 4 + r;
                float val = acc[r] + bias;
                if (oc < 64) qks[p][oc] = bf16r(val);
                else         vs[p][oc - 64] = bf16r(val);
            }
        }
    }
    __syncthreads();
    // write q, k: each [64][32] -> 512 uint2 each
    #pragma unroll
    for (int rep = 0; rep < 2; ++rep) {
        int i = rep * BDIM + t;
        int p = i >> 3, c = (i & 7) * 4;
        *(uint2*)(qg + (base + p) * DD + c) = *(const uint2*)&qks[p][c];
        *(uint2*)(kg + (base + p) * DD + c) = *(const uint2*)&qks[p][32 + c];
    }
    // write vT: 128 c x 8 n-chunks = 1024 uint4
    #pragma unroll
    for (int rep = 0; rep < 4; ++rep) {
        int i = rep * BDIM + t;
        int c = i & 127, nch = i >> 7;
        int p0 = nch * 8;
        uint4 r;
        r.x = (unsigned)vs[p0+0][c] | ((unsigned)vs[p0+1][c] << 16);
        r.y = (unsigned)vs[p0+2][c] | ((unsigned)vs[p0+3][c] << 16);
        r.z = (unsigned)vs[p0+4][c] | ((unsigned)vs[p0+5][c] << 16);
        r.w = (unsigned)vs[p0+6][c] | ((unsigned)vs[p0+7][c] << 16);
        *(uint4*)(vTg + ((long)(b * CC + c)) * NN + n0 + p0) = r;
    }
}

// ---------------- kernel 2: MFMA row softmax stats ----------------
__global__ __launch_bounds__(256) void k_rowstats(
        const ushort_t* __restrict__ qg, const ushort_t* __restrict__ kg,
        float* __restrict__ rowmax, float* __restrict__ rowinv) {
    __shared__ float pm[4][32], ps[4][32];
    int b = blockIdx.x >> 6;
    int nt = (blockIdx.x & 63) * 32;
    int t = threadIdx.x, w = t >> 6, l = t & 63, a = l & 15, g = l >> 4;
    s16x8 qA[2];
    #pragma unroll
    for (int s = 0; s < 2; ++s)
        qA[s] = *(const s16x8*)(qg + ((long)(b * NN + nt + s*16 + a)) * DD + g*8);
    float mx[8], sm[8];
    #pragma unroll
    for (int i = 0; i < 8; ++i) { mx[i] = -1e30f; sm[i] = 0.f; }
    for (int it = 0; it < 32; ++it) {
        int m0 = (it * 4 + w) * 16;
        s16x8 kB = *(const s16x8*)(kg + ((long)(b * NN + m0 + a)) * DD + g*8);
        #pragma unroll
        for (int s = 0; s < 2; ++s) {
            f32x4 D = (f32x4){0.f, 0.f, 0.f, 0.f};
            D = __builtin_amdgcn_mfma_f32_16x16x32_bf16(qA[s], kB, D, 0, 0, 0);
            #pragma unroll
            for (int r = 0; r < 4; ++r) {
                float e = D[r] * SCALE;
                int ix = s * 4 + r;
                float nm = fmaxf(mx[ix], e);
                sm[ix] = sm[ix] * __expf(mx[ix] - nm) + __expf(e - nm);
                mx[ix] = nm;
            }
        }
    }
    #pragma unroll
    for (int off = 1; off < 16; off <<= 1) {
        #pragma unroll
        for (int ix = 0; ix < 8; ++ix) {
            float omx = __shfl_xor(mx[ix], off, 64);
            float osm = __shfl_xor(sm[ix], off, 64);
            float nm = fmaxf(mx[ix], omx);
            sm[ix] = sm[ix] * __expf(mx[ix] - nm) + osm * __expf(omx - nm);
            mx[ix] = nm;
        }
    }
    if (a == 0) {
        #pragma unroll
        for (int s = 0; s < 2; ++s)
            #pragma unroll
            for (int r = 0; r < 4; ++r) {
                pm[w][s * 16 + g * 4 + r] = mx[s * 4 + r];
                ps[w][s * 16 + g * 4 + r] = sm[s * 4 + r];
            }
    }
    __syncthreads();
    if (t < 32) {
        float m0 = pm[0][t], m1 = pm[1][t], m2 = pm[2][t], m3 = pm[3][t];
        float M = fmaxf(fmaxf(m0, m1), fmaxf(m2, m3));
        float S = ps[0][t] * __expf(m0 - M) + ps[1][t] * __expf(m1 - M)
                + ps[2][t] * __expf(m2 - M) + ps[3][t] * __expf(m3 - M);
        rowmax[(long)b * NN + nt + t] = M;
        rowinv[(long)b * NN + nt + t] = 1.f / S;
    }
}

// ---------------- kernel 3: MFMA PV ----------------
__global__ __launch_bounds__(256) void k_pv(
        const ushort_t* __restrict__ qg, const ushort_t* __restrict__ kg,
        const ushort_t* __restrict__ vTg,
        const float* __restrict__ rowmax, const float* __restrict__ rowinv,
        float* __restrict__ xr) {
    __shared__ ushort_t qs[64][40];
    __shared__ ushort_t ks[32][40];
    __shared__ ushort_t vTs[128][72];
    __shared__ ushort_t pT[32][72];
    __shared__ float rmx_s[64], rin_s[64];
    int b = blockIdx.x >> 6;
    int m0 = (blockIdx.x & 63) * 32;
    int t = threadIdx.x, w = t >> 6, l = t & 63, a = l & 15, g = l >> 4;
    if (t < 128) {
        int r = t >> 2, o = (t & 3) * 8;
        *(s16x8*)&ks[r][o] = *(const s16x8*)(kg + ((long)(b * NN + m0 + r)) * DD + o);
    }
    f32x4 acc[2][2];
    #pragma unroll
    for (int i = 0; i < 2; ++i)
        #pragma unroll
        for (int j = 0; j < 2; ++j) acc[i][j] = (f32x4){0.f, 0.f, 0.f, 0.f};
    const ushort_t* vTb = vTg + (long)b * CC * NN;
    for (int nt = 0; nt < NN; nt += 64) {
        __syncthreads();
        {
            int r = t >> 2, o = (t & 3) * 8;
            *(s16x8*)&qs[r][o] = *(const s16x8*)(qg + ((long)(b * NN + nt + r)) * DD + o);
        }
        #pragma unroll
        for (int rep = 0; rep < 4; ++rep) {
            int lin = rep * BDIM + t;
            int c = lin >> 3, o = (lin & 7) * 8;
            *(s16x8*)&vTs[c][o] = *(const s16x8*)(vTb + (long)c * NN + nt + o);
        }
        if (t < 64) rmx_s[t] = rowmax[(long)b * NN + nt + t];
        else if (t < 128) rin_s[t - 64] = rowinv[(long)b * NN + nt + (t - 64)];
        __syncthreads();
        f32x4 e0 = (f32x4){0.f, 0.f, 0.f, 0.f}, e1 = e0;
        s16x8 qf = *(const s16x8*)&qs[w * 16 + a][g * 8];
        e0 = __builtin_amdgcn_mfma_f32_16x16x32_bf16(qf, *(const s16x8*)&ks[a][g * 8], e0, 0, 0, 0);
        e1 = __builtin_amdgcn_mfma_f32_16x16x32_bf16(qf, *(const s16x8*)&ks[16 + a][g * 8], e1, 0, 0, 0);
        float p0[4], p1[4];
        #pragma unroll
        for (int r = 0; r < 4; ++r) {
            int n = w * 16 + g * 4 + r;
            float RM = rmx_s[n], RI = rin_s[n];
            p0[r] = __expf(e0[r] * SCALE - RM) * RI;
            p1[r] = __expf(e1[r] * SCALE - RM) * RI;
        }
        {
            uint2 u0 = make_uint2(pack2(p0[0], p0[1]), pack2(p0[2], p0[3]));
            uint2 u1 = make_uint2(pack2(p1[0], p1[1]), pack2(p1[2], p1[3]));
            *(uint2*)&pT[a][w * 16 + g * 4] = u0;
            *(uint2*)&pT[16 + a][w * 16 + g * 4] = u1;
        }
        __syncthreads();
        #pragma unroll
        for (int k2 = 0; k2 < 2; ++k2) {
            s16x8 A0 = *(const s16x8*)&pT[a][k2 * 32 + g * 8];
            s16x8 A1 = *(const s16x8*)&pT[16 + a][k2 * 32 + g * 8];
            s16x8 B0 = *(const s16x8*)&vTs[w * 32 + a][k2 * 32 + g * 8];
            s16x8 B1 = *(const s16x8*)&vTs[w * 32 + 16 + a][k2 * 32 + g * 8];
            acc[0][0] = __builtin_amdgcn_mfma_f32_16x16x32_bf16(A0, B0, acc[0][0], 0, 0, 0);
            acc[0][1] = __builtin_amdgcn_mfma_f32_16x16x32_bf16(A0, B1, acc[0][1], 0, 0, 0);
            acc[1][0] = __builtin_amdgcn_mfma_f32_16x16x32_bf16(A1, B0, acc[1][0], 0, 0, 0);
            acc[1][1] = __builtin_amdgcn_mfma_f32_16x16x32_bf16(A1, B1, acc[1][1], 0, 0, 0);
        }
    }
    #pragma unroll
    for (int ms = 0; ms < 2; ++ms)
        #pragma unroll
        for (int cs = 0; cs < 2; ++cs)
            #pragma unroll
            for (int r = 0; r < 4; ++r) {
                int m = m0 + ms * 16 + g * 4 + r;
                int c = w * 32 + cs * 16 + a;
                xr[((long)b * NN + m) * CC + c] = acc[ms][cs][r];
            }
}

// ---------------- kernel 4: MFMA t-projection ----------------
// hb = bf16(x + relu(BN1(Wt (x - xr) + bt))). 32 points/block, 512 blocks.
__global__ __launch_bounds__(256) void k_tproj(
        const float* __restrict__ x, const float* __restrict__ xr,
        const ushort_t* __restrict__ Wtb, const float* __restrict__ bt,
        const float* __restrict__ g1, const float* __restrict__ b1,
        const float* __restrict__ m1, const float* __restrict__ v1,
        ushort_t* __restrict__ hb) {
    __shared__ ushort_t ds[32][136];
    __shared__ ushort_t xb[32][136];
    __shared__ ushort_t wt[128][136];
    long base = (long)blockIdx.x * 32;
    int t = threadIdx.x, l = t & 63, wid = t >> 6;
    int ph = wid & 1, fh = wid >> 1;
    int lr = l & 15, lg = l >> 4;
    {
        const float4* xg4 = (const float4*)(x + base * CC);
        const float4* rg4 = (const float4*)(xr + base * CC);
        #pragma unroll
        for (int rep = 0; rep < 4; ++rep) {
            int i = rep * BDIM + t;
            float4 xv = xg4[i], rv = rg4[i];
            int p = i >> 5, c4 = (i & 31) * 4;
            *(uint2*)&ds[p][c4] = make_uint2(pack2(xv.x - rv.x, xv.y - rv.y),
                                             pack2(xv.z - rv.z, xv.w - rv.w));
            *(uint2*)&xb[p][c4] = make_uint2(pack2(xv.x, xv.y), pack2(xv.z, xv.w));
        }
    }
    {
        // wt is 128 rows x 128 halves = 2048 uint4 (NOT 1024 — R5 bug)
        #pragma unroll
        for (int rep = 0; rep < 8; ++rep) {
            int i = rep * BDIM + t;
            int r = i >> 4, c0 = (i & 15) * 8;
            *(uint4*)&wt[r][c0] = *(const uint4*)(Wtb + (long)r * CC + c0);
        }
    }
    __syncthreads();
    s16x8 aF[4];
    #pragma unroll
    for (int ki = 0; ki < 4; ++ki)
        aF[ki] = *(const s16x8*)&ds[ph * 16 + lr][ki * 32 + lg * 8];
    #pragma unroll
    for (int oi = 0; oi < 4; ++oi) {
        int ot = fh * 4 + oi;
        f32x4 acc = (f32x4){0.f, 0.f, 0.f, 0.f};
        #pragma unroll
        for (int ki = 0; ki < 4; ++ki) {
            s16x8 bF = *(const s16x8*)&wt[ot * 16 + lr][ki * 32 + lg * 8];
            acc = __builtin_amdgcn_mfma_f32_16x16x32_bf16(aF[ki], bF, acc, 0, 0, 0);
        }
        int o = ot * 16 + lr;
        float sc = g1[o] * rsqrtf(v1[o] + 1e-5f);
        float mm = m1[o], bb = b1[o], bo = bt[o];
        #pragma unroll
        for (int r = 0; r < 4; ++r) {
            int p = ph * 16 + lg * 4 + r;
            float tv = ((acc[r] + bo) - mm) * sc + bb;
            tv = fmaxf(tv, 0.f);
            hb[(base + p) * CC + o] = bf16r(bf16tof(xb[p][o]) + tv);
        }
    }
}

// ---------------- kernel 5: MFMA fused FF ----------------
__global__ __launch_bounds__(256) void k_ff(
        const ushort_t* __restrict__ hb, const ushort_t* __restrict__ W1b,
        const ushort_t* __restrict__ W2b,
        const float* __restrict__ bf1, const float* __restrict__ bf2,
        const float* __restrict__ g2, const float* __restrict__ b2,
        const float* __restrict__ m2, const float* __restrict__ v2,
        float* __restrict__ out) {
    __shared__ ushort_t hs[32][136];
    __shared__ ushort_t w1s[64][136];
    __shared__ ushort_t w2s[128][72];
    __shared__ ushort_t fss[32][72];
    long pbase = (long)blockIdx.x * 32;
    int t = threadIdx.x;
    for (int i = t; i < 512; i += BDIM) {
        int r = i >> 4, c0 = (i & 15) * 8;
        *(uint4*)&hs[r][c0] = *(const uint4*)(hb + (pbase + r) * CC + c0);
    }
    __syncthreads();
    int l = t & 63, wid = t >> 6;
    int ph = wid & 1;
    int fh = wid >> 1;
    int lr = l & 15, lg = l >> 4;
    s16x8 hA[4];
    #pragma unroll
    for (int ki = 0; ki < 4; ++ki)
        hA[ki] = *(const s16x8*)&hs[ph * 16 + lr][ki * 32 + lg * 8];
    f32x4 acc2[4];
    #pragma unroll
    for (int i = 0; i < 4; ++i) acc2[i] = (f32x4){0.f, 0.f, 0.f, 0.f};

    for (int fc = 0; fc < 8; ++fc) {
        int f0 = fc * 64;
        __syncthreads();
        for (int i = t; i < 1024; i += BDIM) {
            int r = i >> 4, c0 = (i & 15) * 8;
            *(uint4*)&w1s[r][c0] = *(const uint4*)(W1b + (f0 + r) * CC + c0);
        }
        for (int i = t; i < 1024; i += BDIM) {
            int r = i >> 3, c0 = (i & 7) * 8;
            *(uint4*)&w2s[r][c0] = *(const uint4*)(W2b + r * FF + f0 + c0);
        }
        __syncthreads();
        #pragma unroll
        for (int fi = 0; fi < 2; ++fi) {
            int ft = fh * 2 + fi;
            f32x4 a1 = (f32x4){0.f, 0.f, 0.f, 0.f};
            #pragma unroll
            for (int ki = 0; ki < 4; ++ki) {
                s16x8 bfr = *(const s16x8*)&w1s[ft * 16 + lr][ki * 32 + lg * 8];
                a1 = __builtin_amdgcn_mfma_f32_16x16x32_bf16(hA[ki], bfr, a1, 0, 0, 0);
            }
            float bias = bf1[f0 + ft * 16 + lr];
            #pragma unroll
            for (int r = 0; r < 4; ++r) {
                float vv = fmaxf(a1[r] + bias, 0.f);
                fss[ph * 16 + lg * 4 + r][ft * 16 + lr] = bf16r(vv);
            }
        }
        __syncthreads();
        #pragma unroll
        for (int k2 = 0; k2 < 2; ++k2) {
            s16x8 afr = *(const s16x8*)&fss[ph * 16 + lr][k2 * 32 + lg * 8];
            #pragma unroll
            for (int oi = 0; oi < 4; ++oi) {
                int ot = fh * 4 + oi;
                s16x8 bfr = *(const s16x8*)&w2s[ot * 16 + lr][k2 * 32 + lg * 8];
                acc2[oi] = __builtin_amdgcn_mfma_f32_16x16x32_bf16(afr, bfr, acc2[oi], 0, 0, 0);
            }
        }
    }
    #pragma unroll
    for (int oi = 0; oi < 4; ++oi) {
        int o = (fh * 4 + oi) * 16 + lr;
        float sc = g2[o] * rsqrtf(v2[o] + 1e-5f);
        float mm = m2[o], bb = b2[o], bias2 = bf2[o];
        #pragma unroll
        for (int r = 0; r < 4; ++r) {
            int p = ph * 16 + lg * 4 + r;
            float val = bf16tof(hs[p][o]) + acc2[oi][r] + bias2;
            out[(pbase + p) * CC + o] = (val - mm) * sc + bb;
        }
    }
}

extern "C" void kernel_launch(void* const* d_in, const int* in_sizes, int n_in,
                              void* d_out, int out_size, void* d_ws, size_t ws_size,
                              hipStream_t stream) {
    const float* x   = (const float*)d_in[0];
    const float* Wq  = (const float*)d_in[1];
    const float* Wk  = (const float*)d_in[2];
    const float* Wv  = (const float*)d_in[3];
    const float* bv  = (const float*)d_in[4];
    const float* Wt  = (const float*)d_in[5];
    const float* bt  = (const float*)d_in[6];
    const float* g1  = (const float*)d_in[7];
    const float* b1  = (const float*)d_in[8];
    const float* m1  = (const float*)d_in[9];
    const float* v1  = (const float*)d_in[10];
    const float* W1  = (const float*)d_in[11];
    const float* bf1 = (const float*)d_in[12];
    const float* W2  = (const float*)d_in[13];
    const float* bf2 = (const float*)d_in[14];
    const float* g2  = (const float*)d_in[15];
    const float* b2  = (const float*)d_in[16];
    const float* m2  = (const float*)d_in[17];
    const float* v2  = (const float*)d_in[18];
    float* out = (float*)d_out;

    float* ws  = (float*)d_ws;
    float* xr  = ws;                            // NPTS*CC f32
    float* rmx = xr + (long)NPTS * CC;          // NPTS
    float* rin = rmx + NPTS;                    // NPTS
    ushort_t* qg   = (ushort_t*)(rin + NPTS);   // NPTS*DD
    ushort_t* kg   = qg + (long)NPTS * DD;      // NPTS*DD
    ushort_t* vTg  = kg + (long)NPTS * DD;      // NPTS*CC ([b][c][n])
    ushort_t* hbuf = vTg + (long)NPTS * CC;     // NPTS*CC
    ushort_t* W1b  = hbuf + (long)NPTS * CC;    // FF*CC
    ushort_t* W2b  = W1b + FF * CC;             // FF*CC
    ushort_t* Wb   = W2b + FF * CC;             // 192*CC (Wq|Wk|Wv)
    ushort_t* Wtb  = Wb + 192 * CC;             // CC*CC

    k_cvt<<<FF * CC / 4 / BDIM, BDIM, 0, stream>>>(W1, W1b, FF * CC / 4);
    k_cvt<<<FF * CC / 4 / BDIM, BDIM, 0, stream>>>(W2, W2b, FF * CC / 4);
    k_cvt<<<DD * CC / 4 / BDIM, BDIM, 0, stream>>>(Wq, Wb, DD * CC / 4);
    k_cvt<<<DD * CC / 4 / BDIM, BDIM, 0, stream>>>(Wk, Wb + DD * CC, DD * CC / 4);
    k_cvt<<<CC * CC / 4 / BDIM, BDIM, 0, stream>>>(Wv, Wb + 2 * DD * CC, CC * CC / 4);
    k_cvt<<<CC * CC / 4 / BDIM, BDIM, 0, stream>>>(Wt, Wtb, CC * CC / 4);
    k_proj<<<NPTS / 64, BDIM, 0, stream>>>(x, Wb, bv, qg, kg, vTg);
    k_rowstats<<<8 * (NN / 32), BDIM, 0, stream>>>(qg, kg, rmx, rin);
    k_pv<<<8 * (NN / 32), BDIM, 0, stream>>>(qg, kg, vTg, rmx, rin, xr);
    k_tproj<<<NPTS / 32, BDIM, 0, stream>>>(x, xr, Wtb, bt, g1, b1, m1, v1, hbuf);
    k_ff<<<NPTS / 32, BDIM, 0, stream>>>(hbuf, W1b, W2b, bf1, bf2, g2, b2, m2, v2, out);
}

// Round 7
// 96.443 us; speedup vs baseline: 28.5669x; 1.3081x over previous
//
#include <hip/hip_runtime.h>
#include <hip/hip_bf16.h>

#define BDIM 256
#define NPTS (8 * 2048)           // B*N
#define CC 128
#define DD 32
#define FF 512
#define NN 2048
#define SCALE 0.08838834764831845f   // 1/sqrt(128)

typedef float f32x4 __attribute__((ext_vector_type(4)));
typedef short s16x8 __attribute__((ext_vector_type(8)));
typedef unsigned short ushort_t;

__device__ __forceinline__ ushort_t bf16r(float x) {
    __hip_bfloat16 h = __float2bfloat16(x);
    return *reinterpret_cast<ushort_t*>(&h);
}
__device__ __forceinline__ float bf16tof(ushort_t u) {
    unsigned v = ((unsigned)u) << 16;
    return *reinterpret_cast<float*>(&v);
}
__device__ __forceinline__ unsigned pack2(float a, float b) {
    return ((unsigned)bf16r(b) << 16) | (unsigned)bf16r(a);
}

// ---------------- kernel 0: all weights f32 -> bf16, one launch ----------------
// dst layout (halves): W1b[65536] | W2b[65536] | Wq[4096] | Wk[4096] | Wv[16384] | Wt[16384]
__global__ void k_cvt_all(const float* __restrict__ W1, const float* __restrict__ W2,
                          const float* __restrict__ Wq, const float* __restrict__ Wk,
                          const float* __restrict__ Wv, const float* __restrict__ Wt,
                          ushort_t* __restrict__ dst) {
    int i = blockIdx.x * BDIM + threadIdx.x;     // float4 index, 43008 total
    const float* src; int off;
    if (i < 16384)      { src = W1; off = 0; }
    else if (i < 32768) { src = W2; off = 16384; }
    else if (i < 33792) { src = Wq; off = 32768; }
    else if (i < 34816) { src = Wk; off = 33792; }
    else if (i < 38912) { src = Wv; off = 34816; }
    else                { src = Wt; off = 38912; }
    float4 v = ((const float4*)src)[i - off];
    *(uint2*)(dst + (long)i * 4) = make_uint2(pack2(v.x, v.y), pack2(v.z, v.w));
}

// ---------------- kernel 1: MFMA q/k/vT projection ----------------
// grid: NPTS/32 blocks (2 blocks/CU). Wb = packed [192][128] bf16 (Wq|Wk|Wv).
__global__ __launch_bounds__(256) void k_proj(
        const float* __restrict__ x, const ushort_t* __restrict__ Wb,
        const float* __restrict__ bv,
        ushort_t* __restrict__ qg, ushort_t* __restrict__ kg,
        ushort_t* __restrict__ vTg) {
    __shared__ ushort_t xs[32][136];
    __shared__ ushort_t qks[32][72];    // q cols 0-31, k cols 32-63
    __shared__ ushort_t vs[32][136];
    long base = (long)blockIdx.x * 32;
    int b = (int)(base >> 11);
    int n0 = (int)(base & (NN - 1));
    int t = threadIdx.x, w = t >> 6, l = t & 63, a = l & 15, g = l >> 4;
    // stage x tile as bf16: 1024 float4
    {
        const float4* xg4 = (const float4*)(x + base * CC);
        #pragma unroll
        for (int rep = 0; rep < 4; ++rep) {
            int i = rep * BDIM + t;
            float4 v4 = xg4[i];
            int p = i >> 5, c4 = (i & 31) * 4;
            *(uint2*)&xs[p][c4] = make_uint2(pack2(v4.x, v4.y), pack2(v4.z, v4.w));
        }
    }
    // B-frags: wave w owns col-tiles 3w..3w+2 (oc = ctg*16 + a)
    s16x8 bF[3][4];
    #pragma unroll
    for (int ct = 0; ct < 3; ++ct) {
        int ctg = w * 3 + ct;
        #pragma unroll
        for (int ki = 0; ki < 4; ++ki)
            bF[ct][ki] = *(const s16x8*)(Wb + ((long)(ctg * 16 + a)) * CC + ki * 32 + g * 8);
    }
    __syncthreads();
    // 2 row-tiles of 16 points each
    #pragma unroll
    for (int rt = 0; rt < 2; ++rt) {
        s16x8 aF[4];
        #pragma unroll
        for (int ki = 0; ki < 4; ++ki)
            aF[ki] = *(const s16x8*)&xs[rt * 16 + a][ki * 32 + g * 8];
        #pragma unroll
        for (int ct = 0; ct < 3; ++ct) {
            f32x4 acc = (f32x4){0.f, 0.f, 0.f, 0.f};
            #pragma unroll
            for (int ki = 0; ki < 4; ++ki)
                acc = __builtin_amdgcn_mfma_f32_16x16x32_bf16(aF[ki], bF[ct][ki], acc, 0, 0, 0);
            int ctg = w * 3 + ct;
            int oc = ctg * 16 + a;
            float bias = (oc >= 64) ? bv[oc - 64] : 0.f;
            #pragma unroll
            for (int r = 0; r < 4; ++r) {
                int p = rt * 16 + g * 4 + r;
                float val = acc[r] + bias;
                if (oc < 64) qks[p][oc] = bf16r(val);
                else         vs[p][oc - 64] = bf16r(val);
            }
        }
    }
    __syncthreads();
    // write q, k: each [32][32] -> 256 uint2 each
    {
        int p = t >> 3, c = (t & 7) * 4;
        *(uint2*)(qg + (base + p) * DD + c) = *(const uint2*)&qks[p][c];
        *(uint2*)(kg + (base + p) * DD + c) = *(const uint2*)&qks[p][32 + c];
    }
    // write vT: 128 c x 4 n-chunks = 512 uint4
    #pragma unroll
    for (int rep = 0; rep < 2; ++rep) {
        int i = rep * BDIM + t;
        int c = i & 127, nch = i >> 7;
        int p0 = nch * 8;
        uint4 r;
        r.x = (unsigned)vs[p0+0][c] | ((unsigned)vs[p0+1][c] << 16);
        r.y = (unsigned)vs[p0+2][c] | ((unsigned)vs[p0+3][c] << 16);
        r.z = (unsigned)vs[p0+4][c] | ((unsigned)vs[p0+5][c] << 16);
        r.w = (unsigned)vs[p0+6][c] | ((unsigned)vs[p0+7][c] << 16);
        *(uint4*)(vTg + ((long)(b * CC + c)) * NN + n0 + p0) = r;
    }
}

// ---------------- kernel 2: MFMA row softmax sums (no max pass; |e|<~1.2 safe) ----------------
__global__ __launch_bounds__(256) void k_rowstats(
        const ushort_t* __restrict__ qg, const ushort_t* __restrict__ kg,
        float* __restrict__ rowinv) {
    __shared__ float ps[4][32];
    int b = blockIdx.x >> 6;
    int nt = (blockIdx.x & 63) * 32;
    int t = threadIdx.x, w = t >> 6, l = t & 63, a = l & 15, g = l >> 4;
    s16x8 qA[2];
    #pragma unroll
    for (int s = 0; s < 2; ++s)
        qA[s] = *(const s16x8*)(qg + ((long)(b * NN + nt + s*16 + a)) * DD + g*8);
    float sm[8];
    #pragma unroll
    for (int i = 0; i < 8; ++i) sm[i] = 0.f;
    for (int it = 0; it < 32; ++it) {
        int m0 = (it * 4 + w) * 16;
        s16x8 kB = *(const s16x8*)(kg + ((long)(b * NN + m0 + a)) * DD + g*8);
        #pragma unroll
        for (int s = 0; s < 2; ++s) {
            f32x4 D = (f32x4){0.f, 0.f, 0.f, 0.f};
            D = __builtin_amdgcn_mfma_f32_16x16x32_bf16(qA[s], kB, D, 0, 0, 0);
            #pragma unroll
            for (int r = 0; r < 4; ++r)
                sm[s * 4 + r] += __expf(D[r] * SCALE);
        }
    }
    // reduce across the 16 lanes (a) sharing the same n-set
    #pragma unroll
    for (int off = 1; off < 16; off <<= 1)
        #pragma unroll
        for (int ix = 0; ix < 8; ++ix)
            sm[ix] += __shfl_xor(sm[ix], off, 64);
    if (a == 0) {
        #pragma unroll
        for (int s = 0; s < 2; ++s)
            #pragma unroll
            for (int r = 0; r < 4; ++r)
                ps[w][s * 16 + g * 4 + r] = sm[s * 4 + r];
    }
    __syncthreads();
    if (t < 32) {
        float S = ps[0][t] + ps[1][t] + ps[2][t] + ps[3][t];
        rowinv[(long)b * NN + nt + t] = 1.f / S;
    }
}

// ---------------- kernel 3: MFMA PV, 8 waves, reg-staged double buffer ----------------
// grid: 8 b x 64 m-tiles(32) = 512 blocks x 512 thr (2 blocks/CU, 16 waves/CU).
__global__ __launch_bounds__(512) void k_pv(
        const ushort_t* __restrict__ qg, const ushort_t* __restrict__ kg,
        const ushort_t* __restrict__ vTg, const float* __restrict__ rowinv,
        float* __restrict__ xr) {
    __shared__ ushort_t qs[2][64][40];
    __shared__ ushort_t ks[32][40];
    __shared__ ushort_t vTs[2][128][72];
    __shared__ ushort_t pT[32][72];
    __shared__ float rin_s[2][64];
    int b = blockIdx.x >> 6;
    int m0 = (blockIdx.x & 63) * 32;
    int t = threadIdx.x, w = t >> 6, l = t & 63, a = l & 15, g = l >> 4;
    int nsub = w & 3, msub = w >> 2;
    const ushort_t* vTb = vTg + (long)b * CC * NN;
    // stage K tile once (32 rows x 32 d)
    if (t < 128) {
        int r = t >> 2, o = (t & 3) * 8;
        *(s16x8*)&ks[r][o] = *(const s16x8*)(kg + ((long)(b * NN + m0 + r)) * DD + o);
    }
    // prologue: tile 0 -> regs -> LDS buf0
    int qr = t >> 2, qo = (t & 3) * 8;
    int c0 = t >> 3, vo0 = (t & 7) * 8;
    int c1 = (512 + t) >> 3, vo1 = (t & 7) * 8;
    uint4 qreg = make_uint4(0, 0, 0, 0), vreg0, vreg1;
    float rinreg = 0.f;
    if (t < 256) qreg = *(const uint4*)(qg + ((long)(b * NN + qr)) * DD + qo);
    vreg0 = *(const uint4*)(vTb + (long)c0 * NN + vo0);
    vreg1 = *(const uint4*)(vTb + (long)c1 * NN + vo1);
    if (t < 64) rinreg = rowinv[(long)b * NN + t];
    if (t < 256) *(uint4*)&qs[0][qr][qo] = qreg;
    *(uint4*)&vTs[0][c0][vo0] = vreg0;
    *(uint4*)&vTs[0][c1][vo1] = vreg1;
    if (t < 64) rin_s[0][t] = rinreg;

    f32x4 acc[2];
    acc[0] = (f32x4){0.f, 0.f, 0.f, 0.f};
    acc[1] = (f32x4){0.f, 0.f, 0.f, 0.f};
    int cur = 0;
    for (int it = 0; it < 32; ++it) {
        __syncthreads();                       // buf[cur] ready; prev pT reads done
        int ntn = (it + 1) * 64;
        if (it < 31) {                         // issue next-tile loads (in flight over compute)
            if (t < 256) qreg = *(const uint4*)(qg + ((long)(b * NN + ntn + qr)) * DD + qo);
            vreg0 = *(const uint4*)(vTb + (long)c0 * NN + ntn + vo0);
            vreg1 = *(const uint4*)(vTb + (long)c1 * NN + ntn + vo1);
            if (t < 64) rinreg = rowinv[(long)b * NN + ntn + t];
        }
        // E: wave -> (nsub 16n, msub 16m)
        s16x8 qf = *(const s16x8*)&qs[cur][nsub * 16 + a][g * 8];
        s16x8 kf = *(const s16x8*)&ks[msub * 16 + a][g * 8];
        f32x4 e = (f32x4){0.f, 0.f, 0.f, 0.f};
        e = __builtin_amdgcn_mfma_f32_16x16x32_bf16(qf, kf, e, 0, 0, 0);
        float p[4];
        #pragma unroll
        for (int r = 0; r < 4; ++r)
            p[r] = __expf(e[r] * SCALE) * rin_s[cur][nsub * 16 + g * 4 + r];
        *(uint2*)&pT[msub * 16 + a][nsub * 16 + g * 4] =
            make_uint2(pack2(p[0], p[1]), pack2(p[2], p[3]));
        __syncthreads();                       // pT ready
        // PV: wave -> c-slice w*16 (16 c), both m-subs
        #pragma unroll
        for (int k2 = 0; k2 < 2; ++k2) {
            s16x8 A0 = *(const s16x8*)&pT[a][k2 * 32 + g * 8];
            s16x8 A1 = *(const s16x8*)&pT[16 + a][k2 * 32 + g * 8];
            s16x8 Bf = *(const s16x8*)&vTs[cur][w * 16 + a][k2 * 32 + g * 8];
            acc[0] = __builtin_amdgcn_mfma_f32_16x16x32_bf16(A0, Bf, acc[0], 0, 0, 0);
            acc[1] = __builtin_amdgcn_mfma_f32_16x16x32_bf16(A1, Bf, acc[1], 0, 0, 0);
        }
        if (it < 31) {                         // write next tile into other buffer
            if (t < 256) *(uint4*)&qs[cur ^ 1][qr][qo] = qreg;
            *(uint4*)&vTs[cur ^ 1][c0][vo0] = vreg0;
            *(uint4*)&vTs[cur ^ 1][c1][vo1] = vreg1;
            if (t < 64) rin_s[cur ^ 1][t] = rinreg;
        }
        cur ^= 1;
    }
    #pragma unroll
    for (int ms = 0; ms < 2; ++ms)
        #pragma unroll
        for (int r = 0; r < 4; ++r) {
            int m = m0 + ms * 16 + g * 4 + r;
            xr[((long)b * NN + m) * CC + w * 16 + a] = acc[ms][r];
        }
}

// ---------------- kernel 4: MFMA t-projection ----------------
__global__ __launch_bounds__(256) void k_tproj(
        const float* __restrict__ x, const float* __restrict__ xr,
        const ushort_t* __restrict__ Wtb, const float* __restrict__ bt,
        const float* __restrict__ g1, const float* __restrict__ b1,
        const float* __restrict__ m1, const float* __restrict__ v1,
        ushort_t* __restrict__ hb) {
    __shared__ ushort_t ds[32][136];
    __shared__ ushort_t xb[32][136];
    __shared__ ushort_t wt[128][136];
    long base = (long)blockIdx.x * 32;
    int t = threadIdx.x, l = t & 63, wid = t >> 6;
    int ph = wid & 1, fh = wid >> 1;
    int lr = l & 15, lg = l >> 4;
    {
        const float4* xg4 = (const float4*)(x + base * CC);
        const float4* rg4 = (const float4*)(xr + base * CC);
        #pragma unroll
        for (int rep = 0; rep < 4; ++rep) {
            int i = rep * BDIM + t;
            float4 xv = xg4[i], rv = rg4[i];
            int p = i >> 5, c4 = (i & 31) * 4;
            *(uint2*)&ds[p][c4] = make_uint2(pack2(xv.x - rv.x, xv.y - rv.y),
                                             pack2(xv.z - rv.z, xv.w - rv.w));
            *(uint2*)&xb[p][c4] = make_uint2(pack2(xv.x, xv.y), pack2(xv.z, xv.w));
        }
    }
    {
        // wt is 128 rows x 128 halves = 2048 uint4
        #pragma unroll
        for (int rep = 0; rep < 8; ++rep) {
            int i = rep * BDIM + t;
            int r = i >> 4, cc0 = (i & 15) * 8;
            *(uint4*)&wt[r][cc0] = *(const uint4*)(Wtb + (long)r * CC + cc0);
        }
    }
    __syncthreads();
    s16x8 aF[4];
    #pragma unroll
    for (int ki = 0; ki < 4; ++ki)
        aF[ki] = *(const s16x8*)&ds[ph * 16 + lr][ki * 32 + lg * 8];
    #pragma unroll
    for (int oi = 0; oi < 4; ++oi) {
        int ot = fh * 4 + oi;
        f32x4 acc = (f32x4){0.f, 0.f, 0.f, 0.f};
        #pragma unroll
        for (int ki = 0; ki < 4; ++ki) {
            s16x8 bF = *(const s16x8*)&wt[ot * 16 + lr][ki * 32 + lg * 8];
            acc = __builtin_amdgcn_mfma_f32_16x16x32_bf16(aF[ki], bF, acc, 0, 0, 0);
        }
        int o = ot * 16 + lr;
        float sc = g1[o] * rsqrtf(v1[o] + 1e-5f);
        float mm = m1[o], bb = b1[o], bo = bt[o];
        #pragma unroll
        for (int r = 0; r < 4; ++r) {
            int p = ph * 16 + lg * 4 + r;
            float tv = ((acc[r] + bo) - mm) * sc + bb;
            tv = fmaxf(tv, 0.f);
            hb[(base + p) * CC + o] = bf16r(bf16tof(xb[p][o]) + tv);
        }
    }
}

// ---------------- kernel 5: MFMA fused FF ----------------
__global__ __launch_bounds__(256) void k_ff(
        const ushort_t* __restrict__ hb, const ushort_t* __restrict__ W1b,
        const ushort_t* __restrict__ W2b,
        const float* __restrict__ bf1, const float* __restrict__ bf2,
        const float* __restrict__ g2, const float* __restrict__ b2,
        const float* __restrict__ m2, const float* __restrict__ v2,
        float* __restrict__ out) {
    __shared__ ushort_t hs[32][136];
    __shared__ ushort_t w1s[64][136];
    __shared__ ushort_t w2s[128][72];
    __shared__ ushort_t fss[32][72];
    long pbase = (long)blockIdx.x * 32;
    int t = threadIdx.x;
    for (int i = t; i < 512; i += BDIM) {
        int r = i >> 4, c0 = (i & 15) * 8;
        *(uint4*)&hs[r][c0] = *(const uint4*)(hb + (pbase + r) * CC + c0);
    }
    __syncthreads();
    int l = t & 63, wid = t >> 6;
    int ph = wid & 1;
    int fh = wid >> 1;
    int lr = l & 15, lg = l >> 4;
    s16x8 hA[4];
    #pragma unroll
    for (int ki = 0; ki < 4; ++ki)
        hA[ki] = *(const s16x8*)&hs[ph * 16 + lr][ki * 32 + lg * 8];
    f32x4 acc2[4];
    #pragma unroll
    for (int i = 0; i < 4; ++i) acc2[i] = (f32x4){0.f, 0.f, 0.f, 0.f};

    for (int fc = 0; fc < 8; ++fc) {
        int f0 = fc * 64;
        __syncthreads();
        for (int i = t; i < 1024; i += BDIM) {
            int r = i >> 4, c0 = (i & 15) * 8;
            *(uint4*)&w1s[r][c0] = *(const uint4*)(W1b + (f0 + r) * CC + c0);
        }
        for (int i = t; i < 1024; i += BDIM) {
            int r = i >> 3, c0 = (i & 7) * 8;
            *(uint4*)&w2s[r][c0] = *(const uint4*)(W2b + r * FF + f0 + c0);
        }
        __syncthreads();
        #pragma unroll
        for (int fi = 0; fi < 2; ++fi) {
            int ft = fh * 2 + fi;
            f32x4 a1 = (f32x4){0.f, 0.f, 0.f, 0.f};
            #pragma unroll
            for (int ki = 0; ki < 4; ++ki) {
                s16x8 bfr = *(const s16x8*)&w1s[ft * 16 + lr][ki * 32 + lg * 8];
                a1 = __builtin_amdgcn_mfma_f32_16x16x32_bf16(hA[ki], bfr, a1, 0, 0, 0);
            }
            float bias = bf1[f0 + ft * 16 + lr];
            #pragma unroll
            for (int r = 0; r < 4; ++r) {
                float vv = fmaxf(a1[r] + bias, 0.f);
                fss[ph * 16 + lg * 4 + r][ft * 16 + lr] = bf16r(vv);
            }
        }
        __syncthreads();
        #pragma unroll
        for (int k2 = 0; k2 < 2; ++k2) {
            s16x8 afr = *(const s16x8*)&fss[ph * 16 + lr][k2 * 32 + lg * 8];
            #pragma unroll
            for (int oi = 0; oi < 4; ++oi) {
                int ot = fh * 4 + oi;
                s16x8 bfr = *(const s16x8*)&w2s[ot * 16 + lr][k2 * 32 + lg * 8];
                acc2[oi] = __builtin_amdgcn_mfma_f32_16x16x32_bf16(afr, bfr, acc2[oi], 0, 0, 0);
            }
        }
    }
    #pragma unroll
    for (int oi = 0; oi < 4; ++oi) {
        int o = (fh * 4 + oi) * 16 + lr;
        float sc = g2[o] * rsqrtf(v2[o] + 1e-5f);
        float mm = m2[o], bb = b2[o], bias2 = bf2[o];
        #pragma unroll
        for (int r = 0; r < 4; ++r) {
            int p = ph * 16 + lg * 4 + r;
            float val = bf16tof(hs[p][o]) + acc2[oi][r] + bias2;
            out[(pbase + p) * CC + o] = (val - mm) * sc + bb;
        }
    }
}

extern "C" void kernel_launch(void* const* d_in, const int* in_sizes, int n_in,
                              void* d_out, int out_size, void* d_ws, size_t ws_size,
                              hipStream_t stream) {
    const float* x   = (const float*)d_in[0];
    const float* Wq  = (const float*)d_in[1];
    const float* Wk  = (const float*)d_in[2];
    const float* Wv  = (const float*)d_in[3];
    const float* bv  = (const float*)d_in[4];
    const float* Wt  = (const float*)d_in[5];
    const float* bt  = (const float*)d_in[6];
    const float* g1  = (const float*)d_in[7];
    const float* b1  = (const float*)d_in[8];
    const float* m1  = (const float*)d_in[9];
    const float* v1  = (const float*)d_in[10];
    const float* W1  = (const float*)d_in[11];
    const float* bf1 = (const float*)d_in[12];
    const float* W2  = (const float*)d_in[13];
    const float* bf2 = (const float*)d_in[14];
    const float* g2  = (const float*)d_in[15];
    const float* b2  = (const float*)d_in[16];
    const float* m2  = (const float*)d_in[17];
    const float* v2  = (const float*)d_in[18];
    float* out = (float*)d_out;

    float* ws  = (float*)d_ws;
    float* xr  = ws;                            // NPTS*CC f32
    float* rin = xr + (long)NPTS * CC;          // NPTS
    ushort_t* qg   = (ushort_t*)(rin + NPTS);   // NPTS*DD
    ushort_t* kg   = qg + (long)NPTS * DD;      // NPTS*DD
    ushort_t* vTg  = kg + (long)NPTS * DD;      // NPTS*CC ([b][c][n])
    ushort_t* hbuf = vTg + (long)NPTS * CC;     // NPTS*CC
    ushort_t* W1b  = hbuf + (long)NPTS * CC;    // FF*CC
    ushort_t* W2b  = W1b + FF * CC;             // FF*CC
    ushort_t* Wb   = W2b + FF * CC;             // 192*CC (Wq|Wk|Wv)
    ushort_t* Wtb  = Wb + 192 * CC;             // CC*CC

    k_cvt_all<<<168, BDIM, 0, stream>>>(W1, W2, Wq, Wk, Wv, Wt, W1b);
    k_proj<<<NPTS / 32, BDIM, 0, stream>>>(x, Wb, bv, qg, kg, vTg);
    k_rowstats<<<8 * (NN / 32), BDIM, 0, stream>>>(qg, kg, rin);
    k_pv<<<8 * (NN / 32), 512, 0, stream>>>(qg, kg, vTg, rin, xr);
    k_tproj<<<NPTS / 32, BDIM, 0, stream>>>(x, xr, Wtb, bt, g1, b1, m1, v1, hbuf);
    k_ff<<<NPTS / 32, BDIM, 0, stream>>>(hbuf, W1b, W2b, bf1, bf2, g2, b2, m2, v2, out);
}